// Round 10
// baseline (1072.626 us; speedup 1.0000x reference)
//
#include <hip/hip_runtime.h>
#include <cstdint>
#include <cstddef>

typedef unsigned short ushort_t;
typedef short s16x8 __attribute__((ext_vector_type(8)));
typedef float f32x4 __attribute__((ext_vector_type(4)));

// ---------- small helpers ----------
__device__ __forceinline__ float bf2f(ushort_t h){
  union { unsigned int u; float f; } v; v.u = ((unsigned int)h) << 16; return v.f;
}
__device__ __forceinline__ ushort_t f2bf(float x){
  union { float f; unsigned int u; } v; v.f = x;
  unsigned int r = v.u + 0x7FFFu + ((v.u >> 16) & 1u);
  return (ushort_t)(r >> 16);
}
__device__ __forceinline__ float gelu_f(float x){
  return 0.5f * x * (1.0f + erff(x * 0.7071067811865475f));
}
__device__ __forceinline__ float wave_sum(float v){
  #pragma unroll
  for (int o = 32; o; o >>= 1) v += __shfl_xor(v, o);
  return v;
}
__device__ __forceinline__ void block_reduce2(float& s, float& q, float* red){
  s = wave_sum(s); q = wave_sum(q);
  int w = threadIdx.x >> 6, lane = threadIdx.x & 63, nw = blockDim.x >> 6;
  if (lane == 0){ red[w] = s; red[8 + w] = q; }
  __syncthreads();
  float ts = 0.f, tq = 0.f;
  for (int i = 0; i < nw; ++i){ ts += red[i]; tq += red[8 + i]; }
  __syncthreads();
  s = ts; q = tq;
}

#define SSLOT(cc, m) (((cc) & 56) | (((cc) & 7) ^ (((m) ^ ((m) >> 3)) & 7)))

// ---------- fused prep: trunk-LN + 11 transposes + 2 casts + bv2 ----------
struct TDesc { const float* in; ushort_t* out; int K; int N; int start; };
struct PrepArgs {
  const float* states; const float* tv; const float* lng; const float* lnb; ushort_t* xnb;
  TDesc t[11];
  int ntiles_end;
  int cast1_blocks;
  int cast_end;
  const float* memw; ushort_t* memwb;
  const float* csum; ushort_t* csb;
  const float* memb; const float* wv; const float* bvp; float* bv2;
};

__global__ __launch_bounds__(256) void prep_k(PrepArgs a){
  int bid = blockIdx.x, tid = threadIdx.x;
  __shared__ float buf[640];
  __shared__ float red[16];
  __shared__ float tbuf[32][33];
  if (bid < 4096){
    int row = bid;
    float t = a.tv[row];
    for (int i = tid; i < 640; i += 256){
      float v;
      if (i < 512) v = a.states[(size_t)row * 512 + i];
      else {
        int j = i - 512, jj = j & 63;
        float fr = expf(6.907755278982137f * ((float)jj * (1.0f / 63.0f)));
        float ang = 6.283185307179586f * t * fr;
        v = (j < 64) ? sinf(ang) : cosf(ang);
      }
      buf[i] = v;
    }
    __syncthreads();
    float s = 0.f, q = 0.f;
    for (int i = tid; i < 640; i += 256){ float v = buf[i]; s += v; q += v * v; }
    block_reduce2(s, q, red);
    float mean = s * (1.0f / 640.0f);
    float var = q * (1.0f / 640.0f) - mean * mean;
    float rstd = rsqrtf(var + 1e-5f);
    for (int i = tid; i < 640; i += 256)
      a.xnb[(size_t)row * 640 + i] = f2bf((buf[i] - mean) * rstd * a.lng[i] + a.lnb[i]);
    return;
  }
  bid -= 4096;
  if (bid < a.ntiles_end){
    int d = 0;
    #pragma unroll
    for (int i = 1; i < 11; ++i) if (bid >= a.t[i].start) d = i;
    TDesc td = a.t[d];
    int tile = bid - td.start;
    int tilesx = td.N >> 5;
    int n0 = (tile % tilesx) << 5, k0 = (tile / tilesx) << 5;
    int tx = tid & 31, ty = tid >> 5;
    #pragma unroll
    for (int j = 0; j < 32; j += 8)
      tbuf[ty + j][tx] = td.in[(size_t)(k0 + ty + j) * td.N + (n0 + tx)];
    __syncthreads();
    #pragma unroll
    for (int j = 0; j < 32; j += 8)
      td.out[(size_t)(n0 + ty + j) * td.K + (k0 + tx)] = f2bf(tbuf[tx][ty + j]);
  } else if (bid < a.cast_end){
    int ci = bid - a.ntiles_end;
    const float* src; ushort_t* dst; int i;
    if (ci < a.cast1_blocks){ src = a.memw; dst = a.memwb; i = ci * 1024 + tid * 4; }
    else { src = a.csum; dst = a.csb; i = (ci - a.cast1_blocks) * 1024 + tid * 4; }
    float4 v = *(const float4*)(src + i);
    union { ushort_t u[4]; uint2 p; } pk;
    pk.u[0] = f2bf(v.x); pk.u[1] = f2bf(v.y); pk.u[2] = f2bf(v.z); pk.u[3] = f2bf(v.w);
    *(uint2*)(dst + i) = pk.p;
  } else {
    int col = (bid - a.cast_end) * 256 + tid;
    float a0 = 0.f, a1 = 0.f, a2 = 0.f, a3 = 0.f;
    for (int j = 0; j < 1024; j += 4){
      a0 += a.memb[j + 0] * a.wv[(size_t)(j + 0) * 1024 + col];
      a1 += a.memb[j + 1] * a.wv[(size_t)(j + 1) * 1024 + col];
      a2 += a.memb[j + 2] * a.wv[(size_t)(j + 2) * 1024 + col];
      a3 += a.memb[j + 3] * a.wv[(size_t)(j + 3) * 1024 + col];
    }
    a.bv2[col] = a0 + a1 + a2 + a3 + a.bvp[col];
  }
}

// ---------- fused support path (unchanged from R9) ----------
__global__ __launch_bounds__(256, 2) void suppattn_k(
    const float* __restrict__ support, const float* __restrict__ lgw, const float* __restrict__ lbw,
    const ushort_t* __restrict__ U, ushort_t* __restrict__ R)
{
  __shared__ ushort_t S[64 * 512];
  __shared__ ushort_t UG[9 * 512];
  __shared__ float WTf[8][65];
  __shared__ float SUMV[64], SUMSQ[64];
  __shared__ __align__(16) float MEANR[64];
  __shared__ __align__(16) float RSTDR[64];
  __shared__ float PMAX[4][8], PSUM[4][8], PMU[4][8];
  __shared__ float AB[2][8];
  __shared__ float MUH[8];

  int bb = blockIdx.x, tid = threadIdx.x, w = tid >> 6, l = tid & 63;
  const ushort_t* Ub = U + (size_t)bb * 4096;

  #pragma unroll 4
  for (int i = 0; i < 16; ++i){
    int m = i * 4 + w;
    const float* row = support + ((size_t)bb * 64 + m) * 512 + l * 8;
    float4 a0 = *(const float4*)row, a1 = *(const float4*)(row + 4);
    union { ushort_t u[8]; uint4 p; } pk;
    pk.u[0] = f2bf(a0.x); pk.u[1] = f2bf(a0.y); pk.u[2] = f2bf(a0.z); pk.u[3] = f2bf(a0.w);
    pk.u[4] = f2bf(a1.x); pk.u[5] = f2bf(a1.y); pk.u[6] = f2bf(a1.z); pk.u[7] = f2bf(a1.w);
    int byteoff = m * 1024 + (SSLOT(l, m) << 4);
    *(uint4*)((char*)S + byteoff) = pk.p;
  }

  for (int id = tid; id < 576; id += 256){
    int hr8 = id >> 6, cc = id & 63;
    int byteoff = hr8 * 1024 + (((cc & 56) | ((cc & 7) ^ (hr8 & 7))) << 4);
    uint4* dst = (uint4*)((char*)UG + byteoff);
    if (hr8 < 8){
      s16x8 uv = *(const s16x8*)(Ub + hr8 * 512 + cc * 8);
      float4 g0 = *(const float4*)(lgw + cc * 8);
      float4 g1 = *(const float4*)(lgw + cc * 8 + 4);
      float ga[8] = { g0.x, g0.y, g0.z, g0.w, g1.x, g1.y, g1.z, g1.w };
      union { ushort_t u[8]; uint4 p; } pk;
      #pragma unroll
      for (int e = 0; e < 8; ++e) pk.u[e] = f2bf(ga[e] * bf2f((ushort_t)uv[e]));
      *dst = pk.p;
    } else {
      *dst = make_uint4(0x3F803F80u, 0x3F803F80u, 0x3F803F80u, 0x3F803F80u);
    }
  }

  {
    int h0 = 2 * w, h1 = 2 * w + 1;
    s16x8 u0 = *(const s16x8*)(Ub + h0 * 512 + l * 8);
    s16x8 u1 = *(const s16x8*)(Ub + h1 * 512 + l * 8);
    float4 g0 = *(const float4*)(lgw + l * 8), g1 = *(const float4*)(lgw + l * 8 + 4);
    float4 c0 = *(const float4*)(lbw + l * 8), c1 = *(const float4*)(lbw + l * 8 + 4);
    float ga[8] = { g0.x, g0.y, g0.z, g0.w, g1.x, g1.y, g1.z, g1.w };
    float ba[8] = { c0.x, c0.y, c0.z, c0.w, c1.x, c1.y, c1.z, c1.w };
    float A0 = 0.f, B0 = 0.f, A1 = 0.f, B1 = 0.f;
    #pragma unroll
    for (int e = 0; e < 8; ++e){
      float x0 = bf2f((ushort_t)u0[e]), x1 = bf2f((ushort_t)u1[e]);
      A0 += ba[e] * x0; B0 += ga[e] * x0;
      A1 += ba[e] * x1; B1 += ga[e] * x1;
    }
    A0 = wave_sum(A0); B0 = wave_sum(B0); A1 = wave_sum(A1); B1 = wave_sum(B1);
    if (l == 0){ AB[0][h0] = A0; AB[1][h0] = B0; AB[0][h1] = A1; AB[1][h1] = B1; }
  }
  __syncthreads();

  int l15 = l & 15, lk = l >> 4;
  int hr = (l15 < 8) ? l15 : 8;
  int arowb = (w * 16 + l15) * 1024;
  int hrowb = hr * 1024;
  int am = w * 16 + l15;
  f32x4 dacc = (f32x4){0.f, 0.f, 0.f, 0.f};
  f32x4 sacc = (f32x4){0.f, 0.f, 0.f, 0.f};
  #pragma unroll
  for (int ks = 0; ks < 16; ++ks){
    int cc = ks * 4 + lk;
    s16x8 afr = *(const s16x8*)((char*)S + arowb + (SSLOT(cc, am) << 4));
    s16x8 bfr = *(const s16x8*)((char*)UG + hrowb + (((cc & 56) | ((cc & 7) ^ (hr & 7))) << 4));
    dacc = __builtin_amdgcn_mfma_f32_16x16x32_bf16(afr, bfr, dacc, 0, 0, 0);
    sacc = __builtin_amdgcn_mfma_f32_16x16x32_bf16(afr, afr, sacc, 0, 0, 0);
  }
  if (l15 == 8){
    #pragma unroll
    for (int j = 0; j < 4; ++j) SUMV[w * 16 + lk * 4 + j] = dacc[j];
  }
  if ((l15 >> 2) == lk) SUMSQ[w * 16 + l15] = sacc[l15 & 3];
  __syncthreads();
  if (tid < 64){
    float mean = SUMV[tid] * (1.0f / 512.0f);
    float var = SUMSQ[tid] * (1.0f / 512.0f) - mean * mean;
    MEANR[tid] = mean;
    RSTDR[tid] = rsqrtf(var + 1e-5f);
  }
  __syncthreads();

  int r0 = w * 16 + lk * 4;
  float4 mns = *(const float4*)(MEANR + r0);
  float4 rst = *(const float4*)(RSTDR + r0);
  float mn[4] = { mns.x, mns.y, mns.z, mns.w };
  float rs[4] = { rst.x, rst.y, rst.z, rst.w };
  float Ah = AB[0][l15 & 7], Bh = AB[1][l15 & 7];
  float lg[4];
  #pragma unroll
  for (int j = 0; j < 4; ++j)
    lg[j] = 0.08838834764831845f * (rs[j] * (dacc[j] - mn[j] * Bh) + Ah);
  float lmax = fmaxf(fmaxf(lg[0], lg[1]), fmaxf(lg[2], lg[3]));
  lmax = fmaxf(lmax, __shfl_xor(lmax, 16));
  lmax = fmaxf(lmax, __shfl_xor(lmax, 32));
  if (l < 8) PMAX[w][l] = lmax;
  __syncthreads();
  float gmax = fmaxf(fmaxf(PMAX[0][l15 & 7], PMAX[1][l15 & 7]),
                     fmaxf(PMAX[2][l15 & 7], PMAX[3][l15 & 7]));
  float e4[4]; float ls = 0.f, lm = 0.f;
  #pragma unroll
  for (int j = 0; j < 4; ++j){
    e4[j] = __expf(lg[j] - gmax);
    ls += e4[j];
    lm += e4[j] * rs[j] * mn[j];
  }
  ls += __shfl_xor(ls, 16); ls += __shfl_xor(ls, 32);
  lm += __shfl_xor(lm, 16); lm += __shfl_xor(lm, 32);
  if (l < 8){ PSUM[w][l] = ls; PMU[w][l] = lm; }
  __syncthreads();
  float Sh = PSUM[0][l15 & 7] + PSUM[1][l15 & 7] + PSUM[2][l15 & 7] + PSUM[3][l15 & 7];
  float inv = 1.0f / Sh;
  if (l15 < 8){
    #pragma unroll
    for (int j = 0; j < 4; ++j) WTf[l15][r0 + j] = e4[j] * rs[j] * inv;
  }
  if (w == 0 && l < 8){
    MUH[l] = (PMU[0][l] + PMU[1][l] + PMU[2][l] + PMU[3][l]) * inv;
  }
  __syncthreads();

  union { ushort_t u[8]; s16x8 v; } af0, af1;
  af0.v = (s16x8){0,0,0,0,0,0,0,0};
  af1.v = (s16x8){0,0,0,0,0,0,0,0};
  if (l15 < 8){
    #pragma unroll
    for (int e = 0; e < 8; ++e){
      af0.u[e] = f2bf(WTf[l15][lk * 8 + e]);
      af1.u[e] = f2bf(WTf[l15][32 + lk * 8 + e]);
    }
  }
  float mu[4];
  #pragma unroll
  for (int j = 0; j < 4; ++j) mu[j] = (lk < 2) ? MUH[lk * 4 + j] : 0.f;

  const char* Sp = (const char*)S;
  #pragma unroll
  for (int ns = 0; ns < 8; ++ns){
    int c = w * 128 + ns * 16 + l15;
    int cch = c >> 3, cb = (c & 7) * 2;
    int sb = cch & 56, cl = cch & 7;
    union { ushort_t u[8]; s16x8 v; } bf0, bf1;
    #pragma unroll
    for (int e = 0; e < 8; ++e){
      int m0 = lk * 8 + e;
      int m1 = m0 + 32;
      bf0.u[e] = *(const ushort_t*)(Sp + m0 * 1024 + ((sb | (cl ^ ((m0 ^ lk) & 7))) << 4) + cb);
      bf1.u[e] = *(const ushort_t*)(Sp + m1 * 1024 + ((sb | (cl ^ ((m1 ^ (4 + lk)) & 7))) << 4) + cb);
    }
    f32x4 cacc = (f32x4){0.f, 0.f, 0.f, 0.f};
    cacc = __builtin_amdgcn_mfma_f32_16x16x32_bf16(af0.v, bf0.v, cacc, 0, 0, 0);
    cacc = __builtin_amdgcn_mfma_f32_16x16x32_bf16(af1.v, bf1.v, cacc, 0, 0, 0);
    if (lk < 2){
      float gc = lgw[c], bc = lbw[c];
      #pragma unroll
      for (int j = 0; j < 4; ++j){
        int h = lk * 4 + j;
        R[(size_t)bb * 4096 + h * 512 + c] = f2bf(gc * (cacc[j] - mu[j]) + bc);
      }
    }
  }
}

// ---------- persistent stage-executor (generic GEMM/FILM/LN stages + grid barrier) ----------
#define GLL16(gsrc, ldst) \
  __builtin_amdgcn_global_load_lds((const __attribute__((address_space(1))) unsigned int*)(gsrc), \
                                   (__attribute__((address_space(3))) unsigned int*)(ldst), 16, 0, 0)

struct Seg {
  const ushort_t* A; const ushort_t* Bt; const float* bias;
  ushort_t* Cb; float* Cf; const ushort_t* R;
  int lda, ldb, ldc, ldr, gx, K, flags, startTile;  // flags: 1 GELU, 2 BIAS, 4 F32OUT, 16 RESID
};
#define MAXSEG 14
#define MAXSTG 8
struct CoopArgs {
  Seg seg[MAXSEG];
  int stage_seg_start[MAXSTG + 1];
  int stage_ntiles[MAXSTG];
  int stage_type[MAXSTG];   // 0 gemm, 1 film-fuse, 2 ln
  int nstages;
  unsigned* bar;
  // film-fuse params
  const ushort_t* combb; const ushort_t* filmb;
  const float *pg, *pb, *cg, *cbp;
  ushort_t *c2b, *cxb;
  // ln params
  const ushort_t* ln_in; const float *ln_g, *ln_b; ushort_t* ln_out;
};

// two-level sense-reversing grid barrier (per-XCD counters -> global), agent-scope
__device__ __forceinline__ void gbar(unsigned* bar, int nb){
  __syncthreads();
  if (threadIdx.x == 0){
    __threadfence();
    int x = blockIdx.x & 7;
    int q = nb >> 3;
    unsigned gen = __hip_atomic_load(&bar[144], __ATOMIC_ACQUIRE, __HIP_MEMORY_SCOPE_AGENT);
    unsigned v = __hip_atomic_fetch_add(&bar[x * 16], 1u, __ATOMIC_ACQ_REL, __HIP_MEMORY_SCOPE_AGENT);
    if ((int)v == q - 1){
      __hip_atomic_store(&bar[x * 16], 0u, __ATOMIC_RELAXED, __HIP_MEMORY_SCOPE_AGENT);
      unsigned d = __hip_atomic_fetch_add(&bar[128], 1u, __ATOMIC_ACQ_REL, __HIP_MEMORY_SCOPE_AGENT);
      if (d == 7u){
        __hip_atomic_store(&bar[128], 0u, __ATOMIC_RELAXED, __HIP_MEMORY_SCOPE_AGENT);
        __hip_atomic_fetch_add(&bar[144], 1u, __ATOMIC_RELEASE, __HIP_MEMORY_SCOPE_AGENT);
      } else {
        while (__hip_atomic_load(&bar[144], __ATOMIC_ACQUIRE, __HIP_MEMORY_SCOPE_AGENT) == gen)
          __builtin_amdgcn_s_sleep(2);
      }
    } else {
      while (__hip_atomic_load(&bar[144], __ATOMIC_ACQUIRE, __HIP_MEMORY_SCOPE_AGENT) == gen)
        __builtin_amdgcn_s_sleep(2);
    }
    __threadfence();
  }
  __syncthreads();
}

__device__ __forceinline__ void gemm_tile(ushort_t (*smA)[4096], ushort_t (*smB)[4096],
                                          const Seg& g, int m0, int n0){
  __syncthreads();   // protect smem from previous tile's lagging readers
  int tid = threadIdx.x, lane = tid & 63, w = tid >> 6;
  int nk = g.K >> 6;

  auto stage = [&](int buf, int kt){
    int k0 = kt << 6;
    #pragma unroll
    for (int i = 0; i < 2; ++i){
      int c = ((w << 1) + i) * 64 + lane;
      int rowl = c >> 3, sp = c & 7;
      int sg = sp ^ (rowl & 7);
      GLL16(g.A + (size_t)(m0 + rowl) * g.lda + (k0 + sg * 8), &smA[buf][((w << 1) + i) * 512]);
    }
    #pragma unroll
    for (int i = 0; i < 2; ++i){
      int c = ((w << 1) + i) * 64 + lane;
      int rowl = c >> 3, sp = c & 7;
      int sg = sp ^ (rowl & 7);
      GLL16(g.Bt + (size_t)(n0 + rowl) * g.ldb + (k0 + sg * 8), &smB[buf][((w << 1) + i) * 512]);
    }
  };

  int qrow = w >> 1, qcol = w & 1;
  int l15 = lane & 15, lk = lane >> 4, l7 = lane & 7;
  int sb0 = ((0 + lk) ^ l7) << 4;
  int sb1 = ((4 + lk) ^ l7) << 4;
  int arow = (qrow * 32 + l15) * 128;
  int brow = (qcol * 32 + l15) * 128;

  f32x4 acc[2][2];
  #pragma unroll
  for (int m = 0; m < 2; ++m)
    #pragma unroll
    for (int n = 0; n < 2; ++n)
      acc[m][n] = (f32x4){0.f, 0.f, 0.f, 0.f};

  stage(0, 0);
  asm volatile("s_waitcnt vmcnt(0)" ::: "memory");
  __syncthreads();
  for (int kt = 0; kt < nk; ++kt){
    int cur = kt & 1;
    if (kt + 1 < nk) stage((kt + 1) & 1, kt + 1);
    const char* ab = (const char*)&smA[cur][0];
    const char* bbp = (const char*)&smB[cur][0];
    s16x8 af[2][2], bfv[2][2];
    #pragma unroll
    for (int m = 0; m < 2; ++m){
      af[m][0] = *(const s16x8*)(ab + arow + m * 2048 + sb0);
      af[m][1] = *(const s16x8*)(ab + arow + m * 2048 + sb1);
    }
    #pragma unroll
    for (int n = 0; n < 2; ++n){
      bfv[n][0] = *(const s16x8*)(bbp + brow + n * 2048 + sb0);
      bfv[n][1] = *(const s16x8*)(bbp + brow + n * 2048 + sb1);
    }
    #pragma unroll
    for (int kb = 0; kb < 2; ++kb)
      #pragma unroll
      for (int m = 0; m < 2; ++m)
        #pragma unroll
        for (int n = 0; n < 2; ++n)
          acc[m][n] = __builtin_amdgcn_mfma_f32_16x16x32_bf16(af[m][kb], bfv[n][kb], acc[m][n], 0, 0, 0);
    if (kt + 1 < nk){
      asm volatile("s_waitcnt vmcnt(0)" ::: "memory");
      __syncthreads();
    }
  }

  bool fG = g.flags & 1, fB = g.flags & 2, fF = g.flags & 4, fR = g.flags & 16;
  #pragma unroll
  for (int n = 0; n < 2; ++n){
    int col = n0 + qcol * 32 + n * 16 + l15;
    float bvv = fB ? g.bias[col] : 0.0f;
    #pragma unroll
    for (int m = 0; m < 2; ++m){
      int rbase = m0 + qrow * 32 + m * 16 + lk * 4;
      #pragma unroll
      for (int r = 0; r < 4; ++r){
        float x = acc[m][n][r] + bvv;
        if (fG) x = gelu_f(x);
        int row = rbase + r;
        if (fR) x += bf2f(g.R[(size_t)row * g.ldr + col]);
        if (fF) g.Cf[(size_t)row * g.ldc + col] = x;
        else    g.Cb[(size_t)row * g.ldc + col] = f2bf(x);
      }
    }
  }
}

__device__ void film_row(const CoopArgs& a, int row, float* red){
  int tid = threadIdx.x, i = tid * 4;
  union { uint2 p; ushort_t u[4]; } av;
  av.p = *(const uint2*)(a.combb + (size_t)row * 1024 + i);
  float x[4] = { bf2f(av.u[0]), bf2f(av.u[1]), bf2f(av.u[2]), bf2f(av.u[3]) };
  float s = x[0] + x[1] + x[2] + x[3];
  float q = x[0]*x[0] + x[1]*x[1] + x[2]*x[2] + x[3]*x[3];
  block_reduce2(s, q, red);
  float mean = s * (1.0f / 1024.0f), var = q * (1.0f / 1024.0f) - mean * mean;
  float rstd = rsqrtf(var + 1e-5f);
  float4 pgv = *(const float4*)(a.pg + i), pbv = *(const float4*)(a.pb + i);
  union { uint2 p; ushort_t u[4]; } scv, shv;
  scv.p = *(const uint2*)(a.filmb + (size_t)row * 2048 + i);
  shv.p = *(const uint2*)(a.filmb + (size_t)row * 2048 + 1024 + i);
  float c2[4];
  {
    float pgx[4] = { pgv.x, pgv.y, pgv.z, pgv.w };
    float pbx[4] = { pbv.x, pbv.y, pbv.z, pbv.w };
    #pragma unroll
    for (int e = 0; e < 4; ++e){
      float cc = (x[e] - mean) * rstd * pgx[e] + pbx[e];
      c2[e] = (1.0f + bf2f(scv.u[e])) * cc + bf2f(shv.u[e]);
    }
  }
  union { ushort_t u[4]; uint2 p; } pc;
  #pragma unroll
  for (int e = 0; e < 4; ++e) pc.u[e] = f2bf(c2[e]);
  *(uint2*)(a.c2b + (size_t)row * 1024 + i) = pc.p;
  float s2 = c2[0] + c2[1] + c2[2] + c2[3];
  float q2 = c2[0]*c2[0] + c2[1]*c2[1] + c2[2]*c2[2] + c2[3]*c2[3];
  block_reduce2(s2, q2, red);
  float m2 = s2 * (1.0f / 1024.0f), v2 = q2 * (1.0f / 1024.0f) - m2 * m2;
  float r2 = rsqrtf(v2 + 1e-5f);
  float4 cgv = *(const float4*)(a.cg + i), cbv = *(const float4*)(a.cbp + i);
  union { ushort_t u[4]; uint2 p; } pk;
  pk.u[0] = f2bf((c2[0] - m2) * r2 * cgv.x + cbv.x);
  pk.u[1] = f2bf((c2[1] - m2) * r2 * cgv.y + cbv.y);
  pk.u[2] = f2bf((c2[2] - m2) * r2 * cgv.z + cbv.z);
  pk.u[3] = f2bf((c2[3] - m2) * r2 * cgv.w + cbv.w);
  *(uint2*)(a.cxb + (size_t)row * 1024 + i) = pk.p;
}

__device__ void ln_row(const CoopArgs& a, int row, float* red){
  int tid = threadIdx.x, i = tid * 4;
  union { uint2 p; ushort_t u[4]; } vv;
  vv.p = *(const uint2*)(a.ln_in + (size_t)row * 1024 + i);
  float v[4] = { bf2f(vv.u[0]), bf2f(vv.u[1]), bf2f(vv.u[2]), bf2f(vv.u[3]) };
  float s = v[0] + v[1] + v[2] + v[3];
  float q = v[0]*v[0] + v[1]*v[1] + v[2]*v[2] + v[3]*v[3];
  block_reduce2(s, q, red);
  float mean = s * (1.0f / 1024.0f), var = q * (1.0f / 1024.0f) - mean * mean;
  float rstd = rsqrtf(var + 1e-5f);
  union { ushort_t u[4]; uint2 p; } pk;
  #pragma unroll
  for (int e = 0; e < 4; ++e) pk.u[e] = f2bf((v[e] - mean) * rstd * a.ln_g[i + e] + a.ln_b[i + e]);
  *(uint2*)(a.ln_out + (size_t)row * 1024 + i) = pk.p;
}

__global__ __launch_bounds__(256, 4) void coop_k(CoopArgs a){
  __shared__ ushort_t smA[2][4096];
  __shared__ ushort_t smB[2][4096];
  __shared__ float red[16];
  int nb = gridDim.x, bid = blockIdx.x;
  int q = nb >> 3;
  int slid = (bid & 7) * q + (bid >> 3);

  for (int st = 0; st < a.nstages; ++st){
    int type = a.stage_type[st];
    if (type == 0){
      int s0 = a.stage_seg_start[st], s1 = a.stage_seg_start[st + 1];
      int nt = a.stage_ntiles[st];
      for (int t = slid; t < nt; t += nb){
        int si = s0;
        while (si + 1 < s1 && t >= a.seg[si + 1].startTile) ++si;
        Seg g = a.seg[si];
        int tl = t - g.startTile;
        int bx = tl % g.gx, by = tl / g.gx;
        gemm_tile(smA, smB, g, by * 64, bx * 64);
      }
    } else if (type == 1){
      for (int row = bid; row < 4096; row += nb) film_row(a, row, red);
    } else {
      for (int row = bid; row < 4096; row += nb) ln_row(a, row, red);
    }
    if (st + 1 < a.nstages) gbar(a.bar, nb);
  }
}

// ---------- host ----------
extern "C" void kernel_launch(void* const* d_in, const int* in_sizes, int n_in,
                              void* d_out, int out_size, void* d_ws, size_t ws_size,
                              hipStream_t stream)
{
  (void)in_sizes; (void)n_in; (void)out_size;
  const float* states      = (const float*)d_in[0];
  const float* time_values = (const float*)d_in[1];
  const float* class_sum   = (const float*)d_in[2];
  const float* support     = (const float*)d_in[3];
  const float* trunk_ln_g  = (const float*)d_in[4];
  const float* trunk_ln_b  = (const float*)d_in[5];
  const float* trunk_w1    = (const float*)d_in[6];
  const float* trunk_b1    = (const float*)d_in[7];
  const float* trunk_w2    = (const float*)d_in[8];
  const float* trunk_b2    = (const float*)d_in[9];
  const float* mem_ln_g    = (const float*)d_in[10];
  const float* mem_ln_b    = (const float*)d_in[11];
  const float* mem_w       = (const float*)d_in[12];
  const float* mem_b       = (const float*)d_in[13];
  const float* wq          = (const float*)d_in[14];
  const float* bq          = (const float*)d_in[15];
  const float* wk          = (const float*)d_in[16];
  /* d_in[17] = bk: unused (softmax shift invariance) */
  const float* wv          = (const float*)d_in[18];
  const float* bvp         = (const float*)d_in[19];
  const float* wo          = (const float*)d_in[20];
  const float* bo          = (const float*)d_in[21];
  const float* pre_g       = (const float*)d_in[22];
  const float* pre_b       = (const float*)d_in[23];
  const float* film_w      = (const float*)d_in[24];
  const float* film_b      = (const float*)d_in[25];
  const float* cond_g      = (const float*)d_in[26];
  const float* cond_b      = (const float*)d_in[27];
  const float* cond_w1     = (const float*)d_in[28];
  const float* cond_b1     = (const float*)d_in[29];
  const float* cond_w2     = (const float*)d_in[30];
  const float* cond_b2     = (const float*)d_in[31];
  const float* head_g      = (const float*)d_in[32];
  const float* head_bb     = (const float*)d_in[33];
  const float* head_w1     = (const float*)d_in[34];
  const float* head_b1     = (const float*)d_in[35];
  const float* head_w2     = (const float*)d_in[36];
  const float* head_b2     = (const float*)d_in[37];
  float* out = (float*)d_out;

  char* ws = (char*)d_ws;
  size_t off = 0;
  auto alloc = [&](size_t bytes)->char*{
    char* p = ws + off;
    off += (bytes + 255) & ~(size_t)255;
    return p;
  };
  ushort_t* tw1T   = (ushort_t*)alloc((size_t)640 * 1024 * 2);
  ushort_t* tw2T   = (ushort_t*)alloc((size_t)1024 * 1024 * 2);
  ushort_t* wqT    = (ushort_t*)alloc((size_t)1024 * 1024 * 2);
  ushort_t* wkT    = (ushort_t*)alloc((size_t)1024 * 1024 * 2);
  ushort_t* wvT    = (ushort_t*)alloc((size_t)1024 * 1024 * 2);
  ushort_t* woT    = (ushort_t*)alloc((size_t)1024 * 1024 * 2);
  ushort_t* memw_b = (ushort_t*)alloc((size_t)512 * 1024 * 2);
  ushort_t* filmWT = (ushort_t*)alloc((size_t)512 * 2048 * 2);
  ushort_t* cw1T   = (ushort_t*)alloc((size_t)1024 * 1024 * 2);
  ushort_t* cw2T   = (ushort_t*)alloc((size_t)1024 * 1024 * 2);
  ushort_t* hw1T   = (ushort_t*)alloc((size_t)1024 * 1024 * 2);
  ushort_t* hw2T   = (ushort_t*)alloc((size_t)1024 * 512 * 2);
  ushort_t* K2     = (ushort_t*)alloc((size_t)512 * 1024 * 2);
  ushort_t* V2T    = (ushort_t*)alloc((size_t)1024 * 512 * 2);
  float*    bv2    = (float*)   alloc((size_t)1024 * 4);
  ushort_t* xnb    = (ushort_t*)alloc((size_t)4096 * 640 * 2);
  ushort_t* h1     = (ushort_t*)alloc((size_t)4096 * 1024 * 2);
  ushort_t* gb     = (ushort_t*)alloc((size_t)4096 * 1024 * 2);
  ushort_t* qb     = (ushort_t*)alloc((size_t)4096 * 1024 * 2);
  ushort_t* U      = (ushort_t*)alloc((size_t)4096 * 4096 * 2);
  ushort_t* Rb     = (ushort_t*)alloc((size_t)4096 * 4096 * 2);
  ushort_t* sumb   = (ushort_t*)alloc((size_t)4096 * 1024 * 2);
  ushort_t* combb  = (ushort_t*)alloc((size_t)4096 * 1024 * 2);
  ushort_t* csb    = (ushort_t*)alloc((size_t)4096 * 512 * 2);
  ushort_t* filmb  = (ushort_t*)alloc((size_t)4096 * 2048 * 2);
  ushort_t* c2b    = (ushort_t*)alloc((size_t)4096 * 1024 * 2);
  ushort_t* cxb    = (ushort_t*)alloc((size_t)4096 * 1024 * 2);
  ushort_t* c1     = (ushort_t*)alloc((size_t)4096 * 1024 * 2);
  ushort_t* cond2b = (ushort_t*)alloc((size_t)4096 * 1024 * 2);
  ushort_t* hxb    = (ushort_t*)alloc((size_t)4096 * 1024 * 2);
  ushort_t* h3     = (ushort_t*)alloc((size_t)4096 * 1024 * 2);
  unsigned* bar    = (unsigned*)alloc(1024);
  if (off > ws_size) return;

  hipMemsetAsync(bar, 0, 1024, stream);

  PrepArgs pa;
  pa.states = states; pa.tv = time_values; pa.lng = trunk_ln_g; pa.lnb = trunk_ln_b; pa.xnb = xnb;
  int s = 0;
  auto setT = [&](int i, const float* in, ushort_t* o, int K, int N){
    pa.t[i].in = in; pa.t[i].out = o; pa.t[i].K = K; pa.t[i].N = N; pa.t[i].start = s;
    s += (N >> 5) * (K >> 5);
  };
  setT(0, trunk_w1, tw1T, 640, 1024);
  setT(1, trunk_w2, tw2T, 1024, 1024);
  setT(2, wq, wqT, 1024, 1024);
  setT(3, wk, wkT, 1024, 1024);
  setT(4, wv, wvT, 1024, 1024);
  setT(5, wo, woT, 1024, 1024);
  setT(6, film_w, filmWT, 512, 2048);
  setT(7, cond_w1, cw1T, 1024, 1024);
  setT(8, cond_w2, cw2T, 1024, 1024);
  setT(9, head_w1, hw1T, 1024, 1024);
  setT(10, head_w2, hw2T, 1024, 512);
  pa.ntiles_end = s;
  pa.cast1_blocks = (512 * 1024) / 1024;
  pa.cast_end = s + pa.cast1_blocks + (4096 * 512) / 1024;
  pa.memw = mem_w; pa.memwb = memw_b;
  pa.csum = class_sum; pa.csb = csb;
  pa.memb = mem_b; pa.wv = wv; pa.bvp = bvp; pa.bv2 = bv2;
  prep_k<<<4096 + pa.cast_end + 4, 256, 0, stream>>>(pa);

  // grid size: guaranteed co-resident (occupancy query), multiple of 8, capped at 1024
  int occ = 0;
  int nb = 256;
  if (hipOccupancyMaxActiveBlocksPerMultiprocessor(&occ, coop_k, 256, 0) == hipSuccess && occ >= 1){
    nb = occ * 256;
    if (nb > 1024) nb = 1024;
  }
  nb &= ~7;
  if (nb < 8) nb = 8;

  auto mkseg = [](const ushort_t* A, const ushort_t* Bt, const float* bias, ushort_t* Cb, float* Cf,
                  const ushort_t* R, int lda, int ldb, int ldc, int ldr, int gx, int K, int flags, int start)->Seg{
    Seg g; g.A = A; g.Bt = Bt; g.bias = bias; g.Cb = Cb; g.Cf = Cf; g.R = R;
    g.lda = lda; g.ldb = ldb; g.ldc = ldc; g.ldr = ldr; g.gx = gx; g.K = K; g.flags = flags; g.startTile = start;
    return g;
  };

  // coop1: S0 {K2, V2T, film, h1} ; S1 gb ; S2 qb ; S3 U(8z)
  {
    CoopArgs a{};
    a.seg[0]  = mkseg(memw_b, wkT, nullptr, K2, nullptr, nullptr, 1024, 1024, 1024, 0, 16, 1024, 0, 0);
    a.seg[1]  = mkseg(wvT, memw_b, nullptr, V2T, nullptr, nullptr, 1024, 1024, 512, 0, 8, 1024, 0, 128);
    a.seg[2]  = mkseg(csb, filmWT, film_b, filmb, nullptr, nullptr, 512, 512, 2048, 0, 32, 512, 2, 256);
    a.seg[3]  = mkseg(xnb, tw1T, trunk_b1, h1, nullptr, nullptr, 640, 640, 1024, 0, 16, 640, 1|2, 2304);
    a.seg[4]  = mkseg(h1, tw2T, trunk_b2, gb, nullptr, nullptr, 1024, 1024, 1024, 0, 16, 1024, 2, 0);
    a.seg[5]  = mkseg(gb, wqT, bq, qb, nullptr, nullptr, 1024, 1024, 1024, 0, 16, 1024, 2, 0);
    for (int z = 0; z < 8; ++z)
      a.seg[6 + z] = mkseg(qb + z * 128, K2 + z * 128, nullptr, U + z * 512, nullptr, nullptr,
                           1024, 1024, 4096, 0, 8, 128, 0, z * 512);
    int sss[5] = {0, 4, 5, 6, 14};
    int snt[4] = {3328, 1024, 1024, 4096};
    for (int i = 0; i < 5; ++i) a.stage_seg_start[i] = sss[i];
    for (int i = 0; i < 4; ++i){ a.stage_ntiles[i] = snt[i]; a.stage_type[i] = 0; }
    a.nstages = 4;
    a.bar = bar;
    coop_k<<<nb, 256, 0, stream>>>(a);
  }

  suppattn_k<<<4096, 256, 0, stream>>>(support, mem_ln_g, mem_ln_b, U, Rb);

  // coop2: S0 sumb(8z) ; S1 combb ; S2 film-fuse ; S3 c1 ; S4 cond2b ; S5 ln ; S6 h3 ; S7 out
  {
    CoopArgs a{};
    for (int z = 0; z < 8; ++z)
      a.seg[z] = mkseg(Rb + z * 512, V2T + (size_t)z * 65536, bv2 + z * 128, sumb + z * 128, nullptr, nullptr,
                       4096, 512, 1024, 0, 2, 512, 2, z * 128);
    a.seg[8]  = mkseg(sumb, woT, bo, combb, nullptr, gb, 1024, 1024, 1024, 1024, 16, 1024, 2|16, 0);
    a.seg[9]  = mkseg(cxb, cw1T, cond_b1, c1, nullptr, nullptr, 1024, 1024, 1024, 0, 16, 1024, 1|2, 0);
    a.seg[10] = mkseg(c1, cw2T, cond_b2, cond2b, nullptr, c2b, 1024, 1024, 1024, 1024, 16, 1024, 2|16, 0);
    a.seg[11] = mkseg(hxb, hw1T, head_b1, h3, nullptr, nullptr, 1024, 1024, 1024, 0, 16, 1024, 1|2, 0);
    a.seg[12] = mkseg(h3, hw2T, head_b2, nullptr, out, nullptr, 1024, 1024, 512, 0, 8, 1024, 2|4, 0);
    int sss[9] = {0, 8, 9, 9, 10, 11, 11, 12, 13};
    int snt[8] = {1024, 1024, 0, 1024, 1024, 0, 1024, 512};
    int sty[8] = {0, 0, 1, 0, 0, 2, 0, 0};
    for (int i = 0; i < 9; ++i) a.stage_seg_start[i] = sss[i];
    for (int i = 0; i < 8; ++i){ a.stage_ntiles[i] = snt[i]; a.stage_type[i] = sty[i]; }
    a.nstages = 8;
    a.bar = bar;
    a.combb = combb; a.filmb = filmb;
    a.pg = pre_g; a.pb = pre_b; a.cg = cond_g; a.cbp = cond_b;
    a.c2b = c2b; a.cxb = cxb;
    a.ln_in = cond2b; a.ln_g = head_g; a.ln_b = head_bb; a.ln_out = hxb;
    coop_k<<<nb, 256, 0, stream>>>(a);
  }
}

// Round 11
// 469.064 us; speedup vs baseline: 2.2867x; 2.2867x over previous
//
#include <hip/hip_runtime.h>
#include <cstdint>
#include <cstddef>

typedef unsigned short ushort_t;
typedef short s16x8 __attribute__((ext_vector_type(8)));
typedef float f32x4 __attribute__((ext_vector_type(4)));

// ---------- small helpers ----------
__device__ __forceinline__ float bf2f(ushort_t h){
  union { unsigned int u; float f; } v; v.u = ((unsigned int)h) << 16; return v.f;
}
__device__ __forceinline__ ushort_t f2bf(float x){
  union { float f; unsigned int u; } v; v.f = x;
  unsigned int r = v.u + 0x7FFFu + ((v.u >> 16) & 1u);
  return (ushort_t)(r >> 16);
}
__device__ __forceinline__ float gelu_f(float x){
  return 0.5f * x * (1.0f + erff(x * 0.7071067811865475f));
}
__device__ __forceinline__ float wave_sum(float v){
  #pragma unroll
  for (int o = 32; o; o >>= 1) v += __shfl_xor(v, o);
  return v;
}
__device__ __forceinline__ void block_reduce2(float& s, float& q, float* red){
  s = wave_sum(s); q = wave_sum(q);
  int w = threadIdx.x >> 6, lane = threadIdx.x & 63, nw = blockDim.x >> 6;
  if (lane == 0){ red[w] = s; red[8 + w] = q; }
  __syncthreads();
  float ts = 0.f, tq = 0.f;
  for (int i = 0; i < nw; ++i){ ts += red[i]; tq += red[8 + i]; }
  __syncthreads();
  s = ts; q = tq;
}

#define SSLOT(cc, m) (((cc) & 56) | (((cc) & 7) ^ (((m) ^ ((m) >> 3)) & 7)))

// ---------- fused prep: trunk-LN + 11 transposes + 2 casts + bv2 ----------
struct TDesc { const float* in; ushort_t* out; int K; int N; int start; };
struct PrepArgs {
  const float* states; const float* tv; const float* lng; const float* lnb; ushort_t* xnb;
  TDesc t[11];
  int ntiles_end;
  int cast1_blocks;
  int cast_end;
  const float* memw; ushort_t* memwb;
  const float* csum; ushort_t* csb;
  const float* memb; const float* wv; const float* bvp; float* bv2;
};

__global__ __launch_bounds__(256) void prep_k(PrepArgs a){
  int bid = blockIdx.x, tid = threadIdx.x;
  __shared__ float buf[640];
  __shared__ float red[16];
  __shared__ float tbuf[32][33];
  if (bid < 4096){
    int row = bid;
    float t = a.tv[row];
    for (int i = tid; i < 640; i += 256){
      float v;
      if (i < 512) v = a.states[(size_t)row * 512 + i];
      else {
        int j = i - 512, jj = j & 63;
        float fr = expf(6.907755278982137f * ((float)jj * (1.0f / 63.0f)));
        float ang = 6.283185307179586f * t * fr;
        v = (j < 64) ? sinf(ang) : cosf(ang);
      }
      buf[i] = v;
    }
    __syncthreads();
    float s = 0.f, q = 0.f;
    for (int i = tid; i < 640; i += 256){ float v = buf[i]; s += v; q += v * v; }
    block_reduce2(s, q, red);
    float mean = s * (1.0f / 640.0f);
    float var = q * (1.0f / 640.0f) - mean * mean;
    float rstd = rsqrtf(var + 1e-5f);
    for (int i = tid; i < 640; i += 256)
      a.xnb[(size_t)row * 640 + i] = f2bf((buf[i] - mean) * rstd * a.lng[i] + a.lnb[i]);
    return;
  }
  bid -= 4096;
  if (bid < a.ntiles_end){
    int d = 0;
    #pragma unroll
    for (int i = 1; i < 11; ++i) if (bid >= a.t[i].start) d = i;
    TDesc td = a.t[d];
    int tile = bid - td.start;
    int tilesx = td.N >> 5;
    int n0 = (tile % tilesx) << 5, k0 = (tile / tilesx) << 5;
    int tx = tid & 31, ty = tid >> 5;
    #pragma unroll
    for (int j = 0; j < 32; j += 8)
      tbuf[ty + j][tx] = td.in[(size_t)(k0 + ty + j) * td.N + (n0 + tx)];
    __syncthreads();
    #pragma unroll
    for (int j = 0; j < 32; j += 8)
      td.out[(size_t)(n0 + ty + j) * td.K + (k0 + tx)] = f2bf(tbuf[tx][ty + j]);
  } else if (bid < a.cast_end){
    int ci = bid - a.ntiles_end;
    const float* src; ushort_t* dst; int i;
    if (ci < a.cast1_blocks){ src = a.memw; dst = a.memwb; i = ci * 1024 + tid * 4; }
    else { src = a.csum; dst = a.csb; i = (ci - a.cast1_blocks) * 1024 + tid * 4; }
    float4 v = *(const float4*)(src + i);
    union { ushort_t u[4]; uint2 p; } pk;
    pk.u[0] = f2bf(v.x); pk.u[1] = f2bf(v.y); pk.u[2] = f2bf(v.z); pk.u[3] = f2bf(v.w);
    *(uint2*)(dst + i) = pk.p;
  } else {
    int col = (bid - a.cast_end) * 256 + tid;
    float a0 = 0.f, a1 = 0.f, a2 = 0.f, a3 = 0.f;
    for (int j = 0; j < 1024; j += 4){
      a0 += a.memb[j + 0] * a.wv[(size_t)(j + 0) * 1024 + col];
      a1 += a.memb[j + 1] * a.wv[(size_t)(j + 1) * 1024 + col];
      a2 += a.memb[j + 2] * a.wv[(size_t)(j + 2) * 1024 + col];
      a3 += a.memb[j + 3] * a.wv[(size_t)(j + 3) * 1024 + col];
    }
    a.bv2[col] = a0 + a1 + a2 + a3 + a.bvp[col];
  }
}

// ---------- row LN (D=1024), bf16 in -> bf16 out ----------
__global__ __launch_bounds__(256) void ln_rows_k(const ushort_t* __restrict__ in, const float* __restrict__ g,
    const float* __restrict__ b, ushort_t* __restrict__ out, int D){
  int row = blockIdx.x, tid = threadIdx.x, i = tid * 4;
  __shared__ float red[16];
  union { uint2 p; ushort_t u[4]; } vv;
  vv.p = *(const uint2*)(in + (size_t)row * D + i);
  float v[4] = { bf2f(vv.u[0]), bf2f(vv.u[1]), bf2f(vv.u[2]), bf2f(vv.u[3]) };
  float s = v[0] + v[1] + v[2] + v[3];
  float q = v[0]*v[0] + v[1]*v[1] + v[2]*v[2] + v[3]*v[3];
  block_reduce2(s, q, red);
  float invD = 1.0f / (float)D;
  float mean = s * invD, var = q * invD - mean * mean, rstd = rsqrtf(var + 1e-5f);
  union { ushort_t u[4]; uint2 p; } pk;
  #pragma unroll
  for (int e = 0; e < 4; ++e) pk.u[e] = f2bf((v[e] - mean) * rstd * g[i + e] + b[i + e]);
  *(uint2*)(out + (size_t)row * D + i) = pk.p;
}

// combined bf16 in; film bf16 in; c2 bf16 out; cx bf16 out
__global__ __launch_bounds__(256) void fuse_film_k(const ushort_t* __restrict__ combb, const ushort_t* __restrict__ filmb,
    const float* __restrict__ pg, const float* __restrict__ pb,
    const float* __restrict__ cg, const float* __restrict__ cb,
    ushort_t* __restrict__ c2b, ushort_t* __restrict__ cxb){
  int row = blockIdx.x, tid = threadIdx.x, i = tid * 4;
  __shared__ float red[16];
  union { uint2 p; ushort_t u[4]; } av;
  av.p = *(const uint2*)(combb + (size_t)row * 1024 + i);
  float x[4] = { bf2f(av.u[0]), bf2f(av.u[1]), bf2f(av.u[2]), bf2f(av.u[3]) };
  float s = x[0] + x[1] + x[2] + x[3];
  float q = x[0]*x[0] + x[1]*x[1] + x[2]*x[2] + x[3]*x[3];
  block_reduce2(s, q, red);
  float mean = s * (1.0f / 1024.0f), var = q * (1.0f / 1024.0f) - mean * mean;
  float rstd = rsqrtf(var + 1e-5f);
  float4 pgv = *(const float4*)(pg + i), pbv = *(const float4*)(pb + i);
  union { uint2 p; ushort_t u[4]; } scv, shv;
  scv.p = *(const uint2*)(filmb + (size_t)row * 2048 + i);
  shv.p = *(const uint2*)(filmb + (size_t)row * 2048 + 1024 + i);
  float c2[4];
  {
    float pgx[4] = { pgv.x, pgv.y, pgv.z, pgv.w };
    float pbx[4] = { pbv.x, pbv.y, pbv.z, pbv.w };
    #pragma unroll
    for (int e = 0; e < 4; ++e){
      float cc = (x[e] - mean) * rstd * pgx[e] + pbx[e];
      c2[e] = (1.0f + bf2f(scv.u[e])) * cc + bf2f(shv.u[e]);
    }
  }
  union { ushort_t u[4]; uint2 p; } pc;
  #pragma unroll
  for (int e = 0; e < 4; ++e) pc.u[e] = f2bf(c2[e]);
  *(uint2*)(c2b + (size_t)row * 1024 + i) = pc.p;
  float s2 = c2[0] + c2[1] + c2[2] + c2[3];
  float q2 = c2[0]*c2[0] + c2[1]*c2[1] + c2[2]*c2[2] + c2[3]*c2[3];
  block_reduce2(s2, q2, red);
  float m2 = s2 * (1.0f / 1024.0f), v2 = q2 * (1.0f / 1024.0f) - m2 * m2;
  float r2 = rsqrtf(v2 + 1e-5f);
  float4 cgv = *(const float4*)(cg + i), cbv = *(const float4*)(cb + i);
  union { ushort_t u[4]; uint2 p; } pk;
  pk.u[0] = f2bf((c2[0] - m2) * r2 * cgv.x + cbv.x);
  pk.u[1] = f2bf((c2[1] - m2) * r2 * cgv.y + cbv.y);
  pk.u[2] = f2bf((c2[2] - m2) * r2 * cgv.z + cbv.z);
  pk.u[3] = f2bf((c2[3] - m2) * r2 * cgv.w + cbv.w);
  *(uint2*)(cxb + (size_t)row * 1024 + i) = pk.p;
}

// ---------- fused support path (R9, unchanged) ----------
__global__ __launch_bounds__(256, 2) void suppattn_k(
    const float* __restrict__ support, const float* __restrict__ lgw, const float* __restrict__ lbw,
    const ushort_t* __restrict__ U, ushort_t* __restrict__ R)
{
  __shared__ ushort_t S[64 * 512];
  __shared__ ushort_t UG[9 * 512];
  __shared__ float WTf[8][65];
  __shared__ float SUMV[64], SUMSQ[64];
  __shared__ __align__(16) float MEANR[64];
  __shared__ __align__(16) float RSTDR[64];
  __shared__ float PMAX[4][8], PSUM[4][8], PMU[4][8];
  __shared__ float AB[2][8];
  __shared__ float MUH[8];

  int bb = blockIdx.x, tid = threadIdx.x, w = tid >> 6, l = tid & 63;
  const ushort_t* Ub = U + (size_t)bb * 4096;

  #pragma unroll 4
  for (int i = 0; i < 16; ++i){
    int m = i * 4 + w;
    const float* row = support + ((size_t)bb * 64 + m) * 512 + l * 8;
    float4 a0 = *(const float4*)row, a1 = *(const float4*)(row + 4);
    union { ushort_t u[8]; uint4 p; } pk;
    pk.u[0] = f2bf(a0.x); pk.u[1] = f2bf(a0.y); pk.u[2] = f2bf(a0.z); pk.u[3] = f2bf(a0.w);
    pk.u[4] = f2bf(a1.x); pk.u[5] = f2bf(a1.y); pk.u[6] = f2bf(a1.z); pk.u[7] = f2bf(a1.w);
    int byteoff = m * 1024 + (SSLOT(l, m) << 4);
    *(uint4*)((char*)S + byteoff) = pk.p;
  }

  for (int id = tid; id < 576; id += 256){
    int hr8 = id >> 6, cc = id & 63;
    int byteoff = hr8 * 1024 + (((cc & 56) | ((cc & 7) ^ (hr8 & 7))) << 4);
    uint4* dst = (uint4*)((char*)UG + byteoff);
    if (hr8 < 8){
      s16x8 uv = *(const s16x8*)(Ub + hr8 * 512 + cc * 8);
      float4 g0 = *(const float4*)(lgw + cc * 8);
      float4 g1 = *(const float4*)(lgw + cc * 8 + 4);
      float ga[8] = { g0.x, g0.y, g0.z, g0.w, g1.x, g1.y, g1.z, g1.w };
      union { ushort_t u[8]; uint4 p; } pk;
      #pragma unroll
      for (int e = 0; e < 8; ++e) pk.u[e] = f2bf(ga[e] * bf2f((ushort_t)uv[e]));
      *dst = pk.p;
    } else {
      *dst = make_uint4(0x3F803F80u, 0x3F803F80u, 0x3F803F80u, 0x3F803F80u);
    }
  }

  {
    int h0 = 2 * w, h1 = 2 * w + 1;
    s16x8 u0 = *(const s16x8*)(Ub + h0 * 512 + l * 8);
    s16x8 u1 = *(const s16x8*)(Ub + h1 * 512 + l * 8);
    float4 g0 = *(const float4*)(lgw + l * 8), g1 = *(const float4*)(lgw + l * 8 + 4);
    float4 c0 = *(const float4*)(lbw + l * 8), c1 = *(const float4*)(lbw + l * 8 + 4);
    float ga[8] = { g0.x, g0.y, g0.z, g0.w, g1.x, g1.y, g1.z, g1.w };
    float ba[8] = { c0.x, c0.y, c0.z, c0.w, c1.x, c1.y, c1.z, c1.w };
    float A0 = 0.f, B0 = 0.f, A1 = 0.f, B1 = 0.f;
    #pragma unroll
    for (int e = 0; e < 8; ++e){
      float x0 = bf2f((ushort_t)u0[e]), x1 = bf2f((ushort_t)u1[e]);
      A0 += ba[e] * x0; B0 += ga[e] * x0;
      A1 += ba[e] * x1; B1 += ga[e] * x1;
    }
    A0 = wave_sum(A0); B0 = wave_sum(B0); A1 = wave_sum(A1); B1 = wave_sum(B1);
    if (l == 0){ AB[0][h0] = A0; AB[1][h0] = B0; AB[0][h1] = A1; AB[1][h1] = B1; }
  }
  __syncthreads();

  int l15 = l & 15, lk = l >> 4;
  int hr = (l15 < 8) ? l15 : 8;
  int arowb = (w * 16 + l15) * 1024;
  int hrowb = hr * 1024;
  int am = w * 16 + l15;
  f32x4 dacc = (f32x4){0.f, 0.f, 0.f, 0.f};
  f32x4 sacc = (f32x4){0.f, 0.f, 0.f, 0.f};
  #pragma unroll
  for (int ks = 0; ks < 16; ++ks){
    int cc = ks * 4 + lk;
    s16x8 afr = *(const s16x8*)((char*)S + arowb + (SSLOT(cc, am) << 4));
    s16x8 bfr = *(const s16x8*)((char*)UG + hrowb + (((cc & 56) | ((cc & 7) ^ (hr & 7))) << 4));
    dacc = __builtin_amdgcn_mfma_f32_16x16x32_bf16(afr, bfr, dacc, 0, 0, 0);
    sacc = __builtin_amdgcn_mfma_f32_16x16x32_bf16(afr, afr, sacc, 0, 0, 0);
  }
  if (l15 == 8){
    #pragma unroll
    for (int j = 0; j < 4; ++j) SUMV[w * 16 + lk * 4 + j] = dacc[j];
  }
  if ((l15 >> 2) == lk) SUMSQ[w * 16 + l15] = sacc[l15 & 3];
  __syncthreads();
  if (tid < 64){
    float mean = SUMV[tid] * (1.0f / 512.0f);
    float var = SUMSQ[tid] * (1.0f / 512.0f) - mean * mean;
    MEANR[tid] = mean;
    RSTDR[tid] = rsqrtf(var + 1e-5f);
  }
  __syncthreads();

  int r0 = w * 16 + lk * 4;
  float4 mns = *(const float4*)(MEANR + r0);
  float4 rst = *(const float4*)(RSTDR + r0);
  float mn[4] = { mns.x, mns.y, mns.z, mns.w };
  float rs[4] = { rst.x, rst.y, rst.z, rst.w };
  float Ah = AB[0][l15 & 7], Bh = AB[1][l15 & 7];
  float lg[4];
  #pragma unroll
  for (int j = 0; j < 4; ++j)
    lg[j] = 0.08838834764831845f * (rs[j] * (dacc[j] - mn[j] * Bh) + Ah);
  float lmax = fmaxf(fmaxf(lg[0], lg[1]), fmaxf(lg[2], lg[3]));
  lmax = fmaxf(lmax, __shfl_xor(lmax, 16));
  lmax = fmaxf(lmax, __shfl_xor(lmax, 32));
  if (l < 8) PMAX[w][l] = lmax;
  __syncthreads();
  float gmax = fmaxf(fmaxf(PMAX[0][l15 & 7], PMAX[1][l15 & 7]),
                     fmaxf(PMAX[2][l15 & 7], PMAX[3][l15 & 7]));
  float e4[4]; float ls = 0.f, lm = 0.f;
  #pragma unroll
  for (int j = 0; j < 4; ++j){
    e4[j] = __expf(lg[j] - gmax);
    ls += e4[j];
    lm += e4[j] * rs[j] * mn[j];
  }
  ls += __shfl_xor(ls, 16); ls += __shfl_xor(ls, 32);
  lm += __shfl_xor(lm, 16); lm += __shfl_xor(lm, 32);
  if (l < 8){ PSUM[w][l] = ls; PMU[w][l] = lm; }
  __syncthreads();
  float Sh = PSUM[0][l15 & 7] + PSUM[1][l15 & 7] + PSUM[2][l15 & 7] + PSUM[3][l15 & 7];
  float inv = 1.0f / Sh;
  if (l15 < 8){
    #pragma unroll
    for (int j = 0; j < 4; ++j) WTf[l15][r0 + j] = e4[j] * rs[j] * inv;
  }
  if (w == 0 && l < 8){
    MUH[l] = (PMU[0][l] + PMU[1][l] + PMU[2][l] + PMU[3][l]) * inv;
  }
  __syncthreads();

  union { ushort_t u[8]; s16x8 v; } af0, af1;
  af0.v = (s16x8){0,0,0,0,0,0,0,0};
  af1.v = (s16x8){0,0,0,0,0,0,0,0};
  if (l15 < 8){
    #pragma unroll
    for (int e = 0; e < 8; ++e){
      af0.u[e] = f2bf(WTf[l15][lk * 8 + e]);
      af1.u[e] = f2bf(WTf[l15][32 + lk * 8 + e]);
    }
  }
  float mu[4];
  #pragma unroll
  for (int j = 0; j < 4; ++j) mu[j] = (lk < 2) ? MUH[lk * 4 + j] : 0.f;

  const char* Sp = (const char*)S;
  #pragma unroll
  for (int ns = 0; ns < 8; ++ns){
    int c = w * 128 + ns * 16 + l15;
    int cch = c >> 3, cb = (c & 7) * 2;
    int sb = cch & 56, cl = cch & 7;
    union { ushort_t u[8]; s16x8 v; } bf0, bf1;
    #pragma unroll
    for (int e = 0; e < 8; ++e){
      int m0 = lk * 8 + e;
      int m1 = m0 + 32;
      bf0.u[e] = *(const ushort_t*)(Sp + m0 * 1024 + ((sb | (cl ^ ((m0 ^ lk) & 7))) << 4) + cb);
      bf1.u[e] = *(const ushort_t*)(Sp + m1 * 1024 + ((sb | (cl ^ ((m1 ^ (4 + lk)) & 7))) << 4) + cb);
    }
    f32x4 cacc = (f32x4){0.f, 0.f, 0.f, 0.f};
    cacc = __builtin_amdgcn_mfma_f32_16x16x32_bf16(af0.v, bf0.v, cacc, 0, 0, 0);
    cacc = __builtin_amdgcn_mfma_f32_16x16x32_bf16(af1.v, bf1.v, cacc, 0, 0, 0);
    if (lk < 2){
      float gc = lgw[c], bc = lbw[c];
      #pragma unroll
      for (int j = 0; j < 4; ++j){
        int h = lk * 4 + j;
        R[(size_t)bb * 4096 + h * 512 + c] = f2bf(gc * (cacc[j] - mu[j]) + bc);
      }
    }
  }
}

// ---------- GEMM core: 64x64 tile, 3-buffer ring, counted vmcnt(4), 3 blocks/CU ----------
#define GLL16(gsrc, ldst) \
  __builtin_amdgcn_global_load_lds((const __attribute__((address_space(1))) unsigned int*)(gsrc), \
                                   (__attribute__((address_space(3))) unsigned int*)(ldst), 16, 0, 0)

struct GDesc {
  const ushort_t* A; const ushort_t* Bt; const float* bias;
  ushort_t* Cb; const ushort_t* R;
  int lda, ldb, ldcb, ldr;
  int gx, startBlock, flags, K;   // flags: 1=GELU 2=BIAS 8=WBF16 16=RESID
};
struct GSet { GDesc d[3]; int nseg; };

// shared inner loop for both kernels
#define GEMM64_BODY(APTR, BPTR, LDA, LDB, KVAL)                                             \
  int nk = (KVAL) >> 6;                                                                     \
  auto stage = [&](int buf, int kt){                                                        \
    int k0 = kt << 6;                                                                       \
    _Pragma("unroll")                                                                       \
    for (int i = 0; i < 2; ++i){                                                            \
      int c = ((w << 1) + i) * 64 + lane;                                                   \
      int rowl = c >> 3, sp = c & 7;                                                        \
      int sg = sp ^ (rowl & 7);                                                             \
      GLL16((APTR) + (size_t)(m0 + rowl) * (LDA) + (k0 + sg * 8), &smA[buf][((w << 1) + i) * 512]); \
    }                                                                                       \
    _Pragma("unroll")                                                                       \
    for (int i = 0; i < 2; ++i){                                                            \
      int c = ((w << 1) + i) * 64 + lane;                                                   \
      int rowl = c >> 3, sp = c & 7;                                                        \
      int sg = sp ^ (rowl & 7);                                                             \
      GLL16((BPTR) + (size_t)(n0 + rowl) * (LDB) + (k0 + sg * 8), &smB[buf][((w << 1) + i) * 512]); \
    }                                                                                       \
  };                                                                                        \
  int qrow = w >> 1, qcol = w & 1;                                                          \
  int l15 = lane & 15, lk = lane >> 4, l7 = lane & 7;                                       \
  int sb0 = ((0 + lk) ^ l7) << 4;                                                           \
  int sb1 = ((4 + lk) ^ l7) << 4;                                                           \
  int arow = (qrow * 32 + l15) * 128;                                                       \
  int brow = (qcol * 32 + l15) * 128;                                                       \
  f32x4 acc[2][2];                                                                          \
  _Pragma("unroll")                                                                         \
  for (int m = 0; m < 2; ++m)                                                               \
    _Pragma("unroll")                                                                       \
    for (int n = 0; n < 2; ++n)                                                             \
      acc[m][n] = (f32x4){0.f, 0.f, 0.f, 0.f};                                              \
  stage(0, 0);                                                                              \
  if (nk > 1){                                                                              \
    stage(1, 1);                                                                            \
    asm volatile("s_waitcnt vmcnt(4)" ::: "memory");   /* buf0 landed, buf1 in flight */    \
  } else {                                                                                  \
    asm volatile("s_waitcnt vmcnt(0)" ::: "memory");                                        \
  }                                                                                         \
  __syncthreads();                                                                          \
  int cur = 0, st = 2;                                                                      \
  for (int kt = 0; kt < nk; ++kt){                                                          \
    if (kt + 2 < nk) stage(st, kt + 2);                                                     \
    const char* ab = (const char*)&smA[cur][0];                                             \
    const char* bbp = (const char*)&smB[cur][0];                                            \
    s16x8 af[2][2], bfv[2][2];                                                              \
    _Pragma("unroll")                                                                       \
    for (int m = 0; m < 2; ++m){                                                            \
      af[m][0] = *(const s16x8*)(ab + arow + m * 2048 + sb0);                               \
      af[m][1] = *(const s16x8*)(ab + arow + m * 2048 + sb1);                               \
    }                                                                                       \
    _Pragma("unroll")                                                                       \
    for (int n = 0; n < 2; ++n){                                                            \
      bfv[n][0] = *(const s16x8*)(bbp + brow + n * 2048 + sb0);                             \
      bfv[n][1] = *(const s16x8*)(bbp + brow + n * 2048 + sb1);                             \
    }                                                                                       \
    _Pragma("unroll")                                                                       \
    for (int kb = 0; kb < 2; ++kb)                                                          \
      _Pragma("unroll")                                                                     \
      for (int m = 0; m < 2; ++m)                                                           \
        _Pragma("unroll")                                                                   \
        for (int n = 0; n < 2; ++n)                                                         \
          acc[m][n] = __builtin_amdgcn_mfma_f32_16x16x32_bf16(af[m][kb], bfv[n][kb], acc[m][n], 0, 0, 0); \
    if (kt + 1 < nk){                                                                       \
      if (kt + 2 < nk) asm volatile("s_waitcnt vmcnt(4)" ::: "memory");                     \
      else             asm volatile("s_waitcnt vmcnt(0)" ::: "memory");                     \
      __syncthreads();                                                                      \
    }                                                                                       \
    cur = (cur == 2) ? 0 : cur + 1;                                                         \
    st  = (st  == 2) ? 0 : st  + 1;                                                         \
  }

__global__ __launch_bounds__(256, 3) void gemmset_k(GSet gs){
  __shared__ ushort_t smA[3][64 * 64];
  __shared__ ushort_t smB[3][64 * 64];
  int bid = blockIdx.x, tid = threadIdx.x, lane = tid & 63, w = tid >> 6;
  int seg = 0;
  #pragma unroll
  for (int i = 1; i < 3; ++i) if (i < gs.nseg && bid >= gs.d[i].startBlock) seg = i;
  GDesc g = gs.d[seg];
  int lid = bid - g.startBlock;
  {
    int nwg = (seg + 1 < gs.nseg ? gs.d[seg + 1].startBlock : (int)gridDim.x) - g.startBlock;
    int q = nwg >> 3;
    lid = (lid & 7) * q + (lid >> 3);
  }
  int bx = lid % g.gx, by = lid / g.gx;
  int m0 = by * 64, n0 = bx * 64;

  GEMM64_BODY(g.A, g.Bt, g.lda, g.ldb, g.K)

  bool fGELU = g.flags & 1, fBIAS = g.flags & 2, fRES = g.flags & 16;
  #pragma unroll
  for (int n = 0; n < 2; ++n){
    int col = n0 + qcol * 32 + n * 16 + l15;
    float bvv = fBIAS ? g.bias[col] : 0.0f;
    #pragma unroll
    for (int m = 0; m < 2; ++m){
      int rbase = m0 + qrow * 32 + m * 16 + lk * 4;
      #pragma unroll
      for (int r = 0; r < 4; ++r){
        float x = acc[m][n][r] + bvv;
        if (fGELU) x = gelu_f(x);
        int row = rbase + r;
        if (fRES) x += bf2f(g.R[(size_t)row * g.ldr + col]);
        g.Cb[(size_t)row * g.ldcb + col] = f2bf(x);
      }
    }
  }
}

template<bool GELU, bool BIAS, bool WF32, bool WBF16, bool RESID>
__global__ __launch_bounds__(256, 3) void gemm_k(
    const ushort_t* __restrict__ A, int lda, long long aZ,
    const ushort_t* __restrict__ Bt, int ldb, long long bZ,
    const float* __restrict__ bias, long long biasZ,
    float* __restrict__ C, int ldc, long long cZ,
    ushort_t* __restrict__ Cb, int ldcb, long long cbZ,
    const ushort_t* __restrict__ R, int ldr,
    int M, int N, int K)
{
  __shared__ ushort_t smA[3][64 * 64];
  __shared__ ushort_t smB[3][64 * 64];
  int tid = threadIdx.x, lane = tid & 63, w = tid >> 6;
  int z = blockIdx.z;
  A  += (size_t)aZ * z;
  Bt += (size_t)bZ * z;
  if (BIAS)  bias += (size_t)biasZ * z;
  if (WF32)  C    += (size_t)cZ * z;
  if (WBF16) Cb   += (size_t)cbZ * z;

  int gx = gridDim.x, gy = gridDim.y;
  int nwg = gx * gy;
  int bx = blockIdx.x, by = blockIdx.y;
  if ((nwg & 7) == 0 && (gx & (gx - 1)) == 0){
    int lid = bx + gx * by;
    int cpx = nwg >> 3;
    int slid = (lid & 7) * cpx + (lid >> 3);
    int lgx = 31 - __clz(gx);
    bx = slid & (gx - 1);
    by = slid >> lgx;
  }
  int m0 = by * 64, n0 = bx * 64;

  GEMM64_BODY(A, Bt, lda, ldb, K)

  #pragma unroll
  for (int n = 0; n < 2; ++n){
    int col = n0 + qcol * 32 + n * 16 + l15;
    float bvv = BIAS ? bias[col] : 0.0f;
    #pragma unroll
    for (int m = 0; m < 2; ++m){
      int rbase = m0 + qrow * 32 + m * 16 + lk * 4;
      #pragma unroll
      for (int r = 0; r < 4; ++r){
        float x = acc[m][n][r] + bvv;
        if (GELU) x = gelu_f(x);
        int row = rbase + r;
        if (RESID) x += bf2f(R[(size_t)row * ldr + col]);
        if (WF32)  C[(size_t)row * ldc + col] = x;
        if (WBF16) Cb[(size_t)row * ldcb + col] = f2bf(x);
      }
    }
  }
}

// ---------- host ----------
extern "C" void kernel_launch(void* const* d_in, const int* in_sizes, int n_in,
                              void* d_out, int out_size, void* d_ws, size_t ws_size,
                              hipStream_t stream)
{
  (void)in_sizes; (void)n_in; (void)out_size;
  const float* states      = (const float*)d_in[0];
  const float* time_values = (const float*)d_in[1];
  const float* class_sum   = (const float*)d_in[2];
  const float* support     = (const float*)d_in[3];
  const float* trunk_ln_g  = (const float*)d_in[4];
  const float* trunk_ln_b  = (const float*)d_in[5];
  const float* trunk_w1    = (const float*)d_in[6];
  const float* trunk_b1    = (const float*)d_in[7];
  const float* trunk_w2    = (const float*)d_in[8];
  const float* trunk_b2    = (const float*)d_in[9];
  const float* mem_ln_g    = (const float*)d_in[10];
  const float* mem_ln_b    = (const float*)d_in[11];
  const float* mem_w       = (const float*)d_in[12];
  const float* mem_b       = (const float*)d_in[13];
  const float* wq          = (const float*)d_in[14];
  const float* bq          = (const float*)d_in[15];
  const float* wk          = (const float*)d_in[16];
  /* d_in[17] = bk: unused (softmax shift invariance) */
  const float* wv          = (const float*)d_in[18];
  const float* bvp         = (const float*)d_in[19];
  const float* wo          = (const float*)d_in[20];
  const float* bo          = (const float*)d_in[21];
  const float* pre_g       = (const float*)d_in[22];
  const float* pre_b       = (const float*)d_in[23];
  const float* film_w      = (const float*)d_in[24];
  const float* film_b      = (const float*)d_in[25];
  const float* cond_g      = (const float*)d_in[26];
  const float* cond_b      = (const float*)d_in[27];
  const float* cond_w1     = (const float*)d_in[28];
  const float* cond_b1     = (const float*)d_in[29];
  const float* cond_w2     = (const float*)d_in[30];
  const float* cond_b2     = (const float*)d_in[31];
  const float* head_g      = (const float*)d_in[32];
  const float* head_bb     = (const float*)d_in[33];
  const float* head_w1     = (const float*)d_in[34];
  const float* head_b1     = (const float*)d_in[35];
  const float* head_w2     = (const float*)d_in[36];
  const float* head_b2     = (const float*)d_in[37];
  float* out = (float*)d_out;

  char* ws = (char*)d_ws;
  size_t off = 0;
  auto alloc = [&](size_t bytes)->char*{
    char* p = ws + off;
    off += (bytes + 255) & ~(size_t)255;
    return p;
  };
  ushort_t* tw1T   = (ushort_t*)alloc((size_t)640 * 1024 * 2);
  ushort_t* tw2T   = (ushort_t*)alloc((size_t)1024 * 1024 * 2);
  ushort_t* wqT    = (ushort_t*)alloc((size_t)1024 * 1024 * 2);
  ushort_t* wkT    = (ushort_t*)alloc((size_t)1024 * 1024 * 2);
  ushort_t* wvT    = (ushort_t*)alloc((size_t)1024 * 1024 * 2);
  ushort_t* woT    = (ushort_t*)alloc((size_t)1024 * 1024 * 2);
  ushort_t* memw_b = (ushort_t*)alloc((size_t)512 * 1024 * 2);
  ushort_t* filmWT = (ushort_t*)alloc((size_t)512 * 2048 * 2);
  ushort_t* cw1T   = (ushort_t*)alloc((size_t)1024 * 1024 * 2);
  ushort_t* cw2T   = (ushort_t*)alloc((size_t)1024 * 1024 * 2);
  ushort_t* hw1T   = (ushort_t*)alloc((size_t)1024 * 1024 * 2);
  ushort_t* hw2T   = (ushort_t*)alloc((size_t)1024 * 512 * 2);
  ushort_t* K2     = (ushort_t*)alloc((size_t)512 * 1024 * 2);
  ushort_t* V2T    = (ushort_t*)alloc((size_t)1024 * 512 * 2);
  float*    bv2    = (float*)   alloc((size_t)1024 * 4);
  ushort_t* xnb    = (ushort_t*)alloc((size_t)4096 * 640 * 2);
  ushort_t* h1     = (ushort_t*)alloc((size_t)4096 * 1024 * 2);
  ushort_t* gb     = (ushort_t*)alloc((size_t)4096 * 1024 * 2);
  ushort_t* qb     = (ushort_t*)alloc((size_t)4096 * 1024 * 2);
  ushort_t* U      = (ushort_t*)alloc((size_t)4096 * 4096 * 2);
  ushort_t* Rb     = (ushort_t*)alloc((size_t)4096 * 4096 * 2);
  ushort_t* sumb   = (ushort_t*)alloc((size_t)4096 * 1024 * 2);
  ushort_t* combb  = (ushort_t*)alloc((size_t)4096 * 1024 * 2);
  ushort_t* csb    = (ushort_t*)alloc((size_t)4096 * 512 * 2);
  ushort_t* filmb  = (ushort_t*)alloc((size_t)4096 * 2048 * 2);
  ushort_t* c2b    = (ushort_t*)alloc((size_t)4096 * 1024 * 2);
  ushort_t* cxb    = (ushort_t*)alloc((size_t)4096 * 1024 * 2);
  ushort_t* c1     = (ushort_t*)alloc((size_t)4096 * 1024 * 2);
  ushort_t* cond2b = (ushort_t*)alloc((size_t)4096 * 1024 * 2);
  ushort_t* hxb    = (ushort_t*)alloc((size_t)4096 * 1024 * 2);
  ushort_t* h3     = (ushort_t*)alloc((size_t)4096 * 1024 * 2);
  if (off > ws_size) return;

  PrepArgs pa;
  pa.states = states; pa.tv = time_values; pa.lng = trunk_ln_g; pa.lnb = trunk_ln_b; pa.xnb = xnb;
  int s = 0;
  auto setT = [&](int i, const float* in, ushort_t* o, int K, int N){
    pa.t[i].in = in; pa.t[i].out = o; pa.t[i].K = K; pa.t[i].N = N; pa.t[i].start = s;
    s += (N >> 5) * (K >> 5);
  };
  setT(0, trunk_w1, tw1T, 640, 1024);
  setT(1, trunk_w2, tw2T, 1024, 1024);
  setT(2, wq, wqT, 1024, 1024);
  setT(3, wk, wkT, 1024, 1024);
  setT(4, wv, wvT, 1024, 1024);
  setT(5, wo, woT, 1024, 1024);
  setT(6, film_w, filmWT, 512, 2048);
  setT(7, cond_w1, cw1T, 1024, 1024);
  setT(8, cond_w2, cw2T, 1024, 1024);
  setT(9, head_w1, hw1T, 1024, 1024);
  setT(10, head_w2, hw2T, 1024, 512);
  pa.ntiles_end = s;
  pa.cast1_blocks = (512 * 1024) / 1024;
  pa.cast_end = s + pa.cast1_blocks + (4096 * 512) / 1024;
  pa.memw = mem_w; pa.memwb = memw_b;
  pa.csum = class_sum; pa.csb = csb;
  pa.memb = mem_b; pa.wv = wv; pa.bvp = bvp; pa.bv2 = bv2;
  prep_k<<<4096 + pa.cast_end + 4, 256, 0, stream>>>(pa);

  // merged set A: K2, V2T, h1
  {
    GSet gs; gs.nseg = 3;
    gs.d[0] = { memw_b, wkT, nullptr, K2, nullptr, 1024, 1024, 1024, 0, 16, 0, 8, 1024 };
    gs.d[1] = { wvT, memw_b, nullptr, V2T, nullptr, 1024, 1024, 512, 0, 8, 128, 8, 1024 };
    gs.d[2] = { xnb, tw1T, trunk_b1, h1, nullptr, 640, 640, 1024, 0, 16, 256, 1|2|8, 640 };
    gemmset_k<<<1280, 256, 0, stream>>>(gs);
  }

  gemm_k<false, true, false, true, false><<<dim3(16, 64, 1), 256, 0, stream>>>(
      h1, 1024, 0, tw2T, 1024, 0, trunk_b2, 0, nullptr, 0, 0, gb, 1024, 0, nullptr, 0, 4096, 1024, 1024);

  // merged set B: qb, film
  {
    GSet gs; gs.nseg = 2;
    gs.d[0] = { gb, wqT, bq, qb, nullptr, 1024, 1024, 1024, 0, 16, 0, 2|8, 1024 };
    gs.d[1] = { csb, filmWT, film_b, filmb, nullptr, 512, 512, 2048, 0, 32, 1024, 2|8, 512 };
    gs.d[2] = gs.d[1];
    gemmset_k<<<3072, 256, 0, stream>>>(gs);
  }

  gemm_k<false, false, false, true, false><<<dim3(8, 64, 8), 256, 0, stream>>>(
      qb, 1024, 128, K2, 1024, 128, nullptr, 0, nullptr, 0, 0, U, 4096, 512, nullptr, 0, 4096, 512, 128);

  suppattn_k<<<4096, 256, 0, stream>>>(support, mem_ln_g, mem_ln_b, U, Rb);

  gemm_k<false, true, false, true, false><<<dim3(2, 64, 8), 256, 0, stream>>>(
      Rb, 4096, 512, V2T, 512, 65536, bv2, 128, nullptr, 0, 0, sumb, 1024, 128, nullptr, 0, 4096, 128, 512);

  gemm_k<false, true, false, true, true><<<dim3(16, 64, 1), 256, 0, stream>>>(
      sumb, 1024, 0, woT, 1024, 0, bo, 0, nullptr, 0, 0, combb, 1024, 0, gb, 1024, 4096, 1024, 1024);

  fuse_film_k<<<4096, 256, 0, stream>>>(combb, filmb, pre_g, pre_b, cond_g, cond_b, c2b, cxb);

  gemm_k<true, true, false, true, false><<<dim3(16, 64, 1), 256, 0, stream>>>(
      cxb, 1024, 0, cw1T, 1024, 0, cond_b1, 0, nullptr, 0, 0, c1, 1024, 0, nullptr, 0, 4096, 1024, 1024);
  gemm_k<false, true, false, true, true><<<dim3(16, 64, 1), 256, 0, stream>>>(
      c1, 1024, 0, cw2T, 1024, 0, cond_b2, 0, nullptr, 0, 0, cond2b, 1024, 0, c2b, 1024, 4096, 1024, 1024);
  ln_rows_k<<<4096, 256, 0, stream>>>(cond2b, head_g, head_bb, hxb, 1024);
  gemm_k<true, true, false, true, false><<<dim3(16, 64, 1), 256, 0, stream>>>(
      hxb, 1024, 0, hw1T, 1024, 0, head_b1, 0, nullptr, 0, 0, h3, 1024, 0, nullptr, 0, 4096, 1024, 1024);
  gemm_k<false, true, true, false, false><<<dim3(8, 64, 1), 256, 0, stream>>>(
      h3, 1024, 0, hw2T, 1024, 0, head_b2, 0, out, 512, 0, nullptr, 0, 0, nullptr, 0, 4096, 512, 1024);
}

// Round 12
// 404.962 us; speedup vs baseline: 2.6487x; 1.1583x over previous
//
#include <hip/hip_runtime.h>
#include <cstdint>
#include <cstddef>

typedef unsigned short ushort_t;
typedef short s16x8 __attribute__((ext_vector_type(8)));
typedef float f32x4 __attribute__((ext_vector_type(4)));

// ---------- small helpers ----------
__device__ __forceinline__ float bf2f(ushort_t h){
  union { unsigned int u; float f; } v; v.u = ((unsigned int)h) << 16; return v.f;
}
__device__ __forceinline__ ushort_t f2bf(float x){
  union { float f; unsigned int u; } v; v.f = x;
  unsigned int r = v.u + 0x7FFFu + ((v.u >> 16) & 1u);
  return (ushort_t)(r >> 16);
}
__device__ __forceinline__ float gelu_f(float x){
  return 0.5f * x * (1.0f + erff(x * 0.7071067811865475f));
}
__device__ __forceinline__ float wave_sum(float v){
  #pragma unroll
  for (int o = 32; o; o >>= 1) v += __shfl_xor(v, o);
  return v;
}
__device__ __forceinline__ void block_reduce2(float& s, float& q, float* red){
  s = wave_sum(s); q = wave_sum(q);
  int w = threadIdx.x >> 6, lane = threadIdx.x & 63, nw = blockDim.x >> 6;
  if (lane == 0){ red[w] = s; red[8 + w] = q; }
  __syncthreads();
  float ts = 0.f, tq = 0.f;
  for (int i = 0; i < nw; ++i){ ts += red[i]; tq += red[8 + i]; }
  __syncthreads();
  s = ts; q = tq;
}

#define SSLOT(cc, m) (((cc) & 56) | (((cc) & 7) ^ (((m) ^ ((m) >> 3)) & 7)))

// ---------- fused prep: trunk-LN + 11 transposes + 2 casts + bv2 ----------
struct TDesc { const float* in; ushort_t* out; int K; int N; int start; };
struct PrepArgs {
  const float* states; const float* tv; const float* lng; const float* lnb; ushort_t* xnb;
  TDesc t[11];
  int ntiles_end;
  int cast1_blocks;
  int cast_end;
  const float* memw; ushort_t* memwb;
  const float* csum; ushort_t* csb;
  const float* memb; const float* wv; const float* bvp; float* bv2;
};

__global__ __launch_bounds__(256) void prep_k(PrepArgs a){
  int bid = blockIdx.x, tid = threadIdx.x;
  __shared__ float buf[640];
  __shared__ float red[16];
  __shared__ float tbuf[32][33];
  if (bid < 4096){
    int row = bid;
    float t = a.tv[row];
    for (int i = tid; i < 640; i += 256){
      float v;
      if (i < 512) v = a.states[(size_t)row * 512 + i];
      else {
        int j = i - 512, jj = j & 63;
        float fr = expf(6.907755278982137f * ((float)jj * (1.0f / 63.0f)));
        float ang = 6.283185307179586f * t * fr;
        v = (j < 64) ? sinf(ang) : cosf(ang);
      }
      buf[i] = v;
    }
    __syncthreads();
    float s = 0.f, q = 0.f;
    for (int i = tid; i < 640; i += 256){ float v = buf[i]; s += v; q += v * v; }
    block_reduce2(s, q, red);
    float mean = s * (1.0f / 640.0f);
    float var = q * (1.0f / 640.0f) - mean * mean;
    float rstd = rsqrtf(var + 1e-5f);
    for (int i = tid; i < 640; i += 256)
      a.xnb[(size_t)row * 640 + i] = f2bf((buf[i] - mean) * rstd * a.lng[i] + a.lnb[i]);
    return;
  }
  bid -= 4096;
  if (bid < a.ntiles_end){
    int d = 0;
    #pragma unroll
    for (int i = 1; i < 11; ++i) if (bid >= a.t[i].start) d = i;
    TDesc td = a.t[d];
    int tile = bid - td.start;
    int tilesx = td.N >> 5;
    int n0 = (tile % tilesx) << 5, k0 = (tile / tilesx) << 5;
    int tx = tid & 31, ty = tid >> 5;
    #pragma unroll
    for (int j = 0; j < 32; j += 8)
      tbuf[ty + j][tx] = td.in[(size_t)(k0 + ty + j) * td.N + (n0 + tx)];
    __syncthreads();
    #pragma unroll
    for (int j = 0; j < 32; j += 8)
      td.out[(size_t)(n0 + ty + j) * td.K + (k0 + tx)] = f2bf(tbuf[tx][ty + j]);
  } else if (bid < a.cast_end){
    int ci = bid - a.ntiles_end;
    const float* src; ushort_t* dst; int i;
    if (ci < a.cast1_blocks){ src = a.memw; dst = a.memwb; i = ci * 1024 + tid * 4; }
    else { src = a.csum; dst = a.csb; i = (ci - a.cast1_blocks) * 1024 + tid * 4; }
    float4 v = *(const float4*)(src + i);
    union { ushort_t u[4]; uint2 p; } pk;
    pk.u[0] = f2bf(v.x); pk.u[1] = f2bf(v.y); pk.u[2] = f2bf(v.z); pk.u[3] = f2bf(v.w);
    *(uint2*)(dst + i) = pk.p;
  } else {
    int col = (bid - a.cast_end) * 256 + tid;
    float a0 = 0.f, a1 = 0.f, a2 = 0.f, a3 = 0.f;
    for (int j = 0; j < 1024; j += 4){
      a0 += a.memb[j + 0] * a.wv[(size_t)(j + 0) * 1024 + col];
      a1 += a.memb[j + 1] * a.wv[(size_t)(j + 1) * 1024 + col];
      a2 += a.memb[j + 2] * a.wv[(size_t)(j + 2) * 1024 + col];
      a3 += a.memb[j + 3] * a.wv[(size_t)(j + 3) * 1024 + col];
    }
    a.bv2[col] = a0 + a1 + a2 + a3 + a.bvp[col];
  }
}

// ---------- row LN (D=1024), bf16 in -> bf16 out ----------
__global__ __launch_bounds__(256) void ln_rows_k(const ushort_t* __restrict__ in, const float* __restrict__ g,
    const float* __restrict__ b, ushort_t* __restrict__ out, int D){
  int row = blockIdx.x, tid = threadIdx.x, i = tid * 4;
  __shared__ float red[16];
  union { uint2 p; ushort_t u[4]; } vv;
  vv.p = *(const uint2*)(in + (size_t)row * D + i);
  float v[4] = { bf2f(vv.u[0]), bf2f(vv.u[1]), bf2f(vv.u[2]), bf2f(vv.u[3]) };
  float s = v[0] + v[1] + v[2] + v[3];
  float q = v[0]*v[0] + v[1]*v[1] + v[2]*v[2] + v[3]*v[3];
  block_reduce2(s, q, red);
  float invD = 1.0f / (float)D;
  float mean = s * invD, var = q * invD - mean * mean, rstd = rsqrtf(var + 1e-5f);
  union { ushort_t u[4]; uint2 p; } pk;
  #pragma unroll
  for (int e = 0; e < 4; ++e) pk.u[e] = f2bf((v[e] - mean) * rstd * g[i + e] + b[i + e]);
  *(uint2*)(out + (size_t)row * D + i) = pk.p;
}

// combined bf16 in; film bf16 in; c2 bf16 out; cx bf16 out
__global__ __launch_bounds__(256) void fuse_film_k(const ushort_t* __restrict__ combb, const ushort_t* __restrict__ filmb,
    const float* __restrict__ pg, const float* __restrict__ pb,
    const float* __restrict__ cg, const float* __restrict__ cb,
    ushort_t* __restrict__ c2b, ushort_t* __restrict__ cxb){
  int row = blockIdx.x, tid = threadIdx.x, i = tid * 4;
  __shared__ float red[16];
  union { uint2 p; ushort_t u[4]; } av;
  av.p = *(const uint2*)(combb + (size_t)row * 1024 + i);
  float x[4] = { bf2f(av.u[0]), bf2f(av.u[1]), bf2f(av.u[2]), bf2f(av.u[3]) };
  float s = x[0] + x[1] + x[2] + x[3];
  float q = x[0]*x[0] + x[1]*x[1] + x[2]*x[2] + x[3]*x[3];
  block_reduce2(s, q, red);
  float mean = s * (1.0f / 1024.0f), var = q * (1.0f / 1024.0f) - mean * mean;
  float rstd = rsqrtf(var + 1e-5f);
  float4 pgv = *(const float4*)(pg + i), pbv = *(const float4*)(pb + i);
  union { uint2 p; ushort_t u[4]; } scv, shv;
  scv.p = *(const uint2*)(filmb + (size_t)row * 2048 + i);
  shv.p = *(const uint2*)(filmb + (size_t)row * 2048 + 1024 + i);
  float c2[4];
  {
    float pgx[4] = { pgv.x, pgv.y, pgv.z, pgv.w };
    float pbx[4] = { pbv.x, pbv.y, pbv.z, pbv.w };
    #pragma unroll
    for (int e = 0; e < 4; ++e){
      float cc = (x[e] - mean) * rstd * pgx[e] + pbx[e];
      c2[e] = (1.0f + bf2f(scv.u[e])) * cc + bf2f(shv.u[e]);
    }
  }
  union { ushort_t u[4]; uint2 p; } pc;
  #pragma unroll
  for (int e = 0; e < 4; ++e) pc.u[e] = f2bf(c2[e]);
  *(uint2*)(c2b + (size_t)row * 1024 + i) = pc.p;
  float s2 = c2[0] + c2[1] + c2[2] + c2[3];
  float q2 = c2[0]*c2[0] + c2[1]*c2[1] + c2[2]*c2[2] + c2[3]*c2[3];
  block_reduce2(s2, q2, red);
  float m2 = s2 * (1.0f / 1024.0f), v2 = q2 * (1.0f / 1024.0f) - m2 * m2;
  float r2 = rsqrtf(v2 + 1e-5f);
  float4 cgv = *(const float4*)(cg + i), cbv = *(const float4*)(cb + i);
  union { ushort_t u[4]; uint2 p; } pk;
  pk.u[0] = f2bf((c2[0] - m2) * r2 * cgv.x + cbv.x);
  pk.u[1] = f2bf((c2[1] - m2) * r2 * cgv.y + cbv.y);
  pk.u[2] = f2bf((c2[2] - m2) * r2 * cgv.z + cbv.z);
  pk.u[3] = f2bf((c2[3] - m2) * r2 * cgv.w + cbv.w);
  *(uint2*)(cxb + (size_t)row * 1024 + i) = pk.p;
}

// ---------- fused support path: loads issued first; MFMA for dotv, stats, ctx ----------
__global__ __launch_bounds__(256, 2) void suppattn_k(
    const float* __restrict__ support, const float* __restrict__ lgw, const float* __restrict__ lbw,
    const ushort_t* __restrict__ U, ushort_t* __restrict__ R)
{
  __shared__ ushort_t S[64 * 512];
  __shared__ ushort_t UG[9 * 512];
  __shared__ float WTf[8][65];
  __shared__ float SUMV[64], SUMSQ[64];
  __shared__ __align__(16) float MEANR[64];
  __shared__ __align__(16) float RSTDR[64];
  __shared__ float PMAX[4][8], PSUM[4][8], PMU[4][8];
  __shared__ float AB[2][8];
  __shared__ float MUH[8];

  int bb = blockIdx.x, tid = threadIdx.x, w = tid >> 6, l = tid & 63;
  const ushort_t* Ub = U + (size_t)bb * 4096;

  // ---- support stream FIRST ----
  #pragma unroll 4
  for (int i = 0; i < 16; ++i){
    int m = i * 4 + w;
    const float* row = support + ((size_t)bb * 64 + m) * 512 + l * 8;
    float4 a0 = *(const float4*)row, a1 = *(const float4*)(row + 4);
    union { ushort_t u[8]; uint4 p; } pk;
    pk.u[0] = f2bf(a0.x); pk.u[1] = f2bf(a0.y); pk.u[2] = f2bf(a0.z); pk.u[3] = f2bf(a0.w);
    pk.u[4] = f2bf(a1.x); pk.u[5] = f2bf(a1.y); pk.u[6] = f2bf(a1.z); pk.u[7] = f2bf(a1.w);
    int byteoff = m * 1024 + (SSLOT(l, m) << 4);
    *(uint4*)((char*)S + byteoff) = pk.p;
  }

  // UG[h][c] = g[c]*u[h][c]; row 8 = bf16(1.0)
  for (int id = tid; id < 576; id += 256){
    int hr8 = id >> 6, cc = id & 63;
    int byteoff = hr8 * 1024 + (((cc & 56) | ((cc & 7) ^ (hr8 & 7))) << 4);
    uint4* dst = (uint4*)((char*)UG + byteoff);
    if (hr8 < 8){
      s16x8 uv = *(const s16x8*)(Ub + hr8 * 512 + cc * 8);
      float4 g0 = *(const float4*)(lgw + cc * 8);
      float4 g1 = *(const float4*)(lgw + cc * 8 + 4);
      float ga[8] = { g0.x, g0.y, g0.z, g0.w, g1.x, g1.y, g1.z, g1.w };
      union { ushort_t u[8]; uint4 p; } pk;
      #pragma unroll
      for (int e = 0; e < 8; ++e) pk.u[e] = f2bf(ga[e] * bf2f((ushort_t)uv[e]));
      *dst = pk.p;
    } else {
      *dst = make_uint4(0x3F803F80u, 0x3F803F80u, 0x3F803F80u, 0x3F803F80u);
    }
  }

  // A_h = b.u_h, B_h = g.u_h (wave w: heads 2w, 2w+1)
  {
    int h0 = 2 * w, h1 = 2 * w + 1;
    s16x8 u0 = *(const s16x8*)(Ub + h0 * 512 + l * 8);
    s16x8 u1 = *(const s16x8*)(Ub + h1 * 512 + l * 8);
    float4 g0 = *(const float4*)(lgw + l * 8), g1 = *(const float4*)(lgw + l * 8 + 4);
    float4 c0 = *(const float4*)(lbw + l * 8), c1 = *(const float4*)(lbw + l * 8 + 4);
    float ga[8] = { g0.x, g0.y, g0.z, g0.w, g1.x, g1.y, g1.z, g1.w };
    float ba[8] = { c0.x, c0.y, c0.z, c0.w, c1.x, c1.y, c1.z, c1.w };
    float A0 = 0.f, B0 = 0.f, A1 = 0.f, B1 = 0.f;
    #pragma unroll
    for (int e = 0; e < 8; ++e){
      float x0 = bf2f((ushort_t)u0[e]), x1 = bf2f((ushort_t)u1[e]);
      A0 += ba[e] * x0; B0 += ga[e] * x0;
      A1 += ba[e] * x1; B1 += ga[e] * x1;
    }
    A0 = wave_sum(A0); B0 = wave_sum(B0); A1 = wave_sum(A1); B1 = wave_sum(B1);
    if (l == 0){ AB[0][h0] = A0; AB[1][h0] = B0; AB[0][h1] = A1; AB[1][h1] = B1; }
  }
  __syncthreads();

  // MFMA: dotv (+rowsum via ones col8) and diag(V.V^T) = sumsq
  int l15 = l & 15, lk = l >> 4;
  int hr = (l15 < 8) ? l15 : 8;
  int arowb = (w * 16 + l15) * 1024;
  int hrowb = hr * 1024;
  int am = w * 16 + l15;
  f32x4 dacc = (f32x4){0.f, 0.f, 0.f, 0.f};
  f32x4 sacc = (f32x4){0.f, 0.f, 0.f, 0.f};
  #pragma unroll
  for (int ks = 0; ks < 16; ++ks){
    int cc = ks * 4 + lk;
    s16x8 afr = *(const s16x8*)((char*)S + arowb + (SSLOT(cc, am) << 4));
    s16x8 bfr = *(const s16x8*)((char*)UG + hrowb + (((cc & 56) | ((cc & 7) ^ (hr & 7))) << 4));
    dacc = __builtin_amdgcn_mfma_f32_16x16x32_bf16(afr, bfr, dacc, 0, 0, 0);
    sacc = __builtin_amdgcn_mfma_f32_16x16x32_bf16(afr, afr, sacc, 0, 0, 0);
  }
  if (l15 == 8){
    #pragma unroll
    for (int j = 0; j < 4; ++j) SUMV[w * 16 + lk * 4 + j] = dacc[j];
  }
  if ((l15 >> 2) == lk) SUMSQ[w * 16 + l15] = sacc[l15 & 3];
  __syncthreads();
  if (tid < 64){
    float mean = SUMV[tid] * (1.0f / 512.0f);
    float var = SUMSQ[tid] * (1.0f / 512.0f) - mean * mean;
    MEANR[tid] = mean;
    RSTDR[tid] = rsqrtf(var + 1e-5f);
  }
  __syncthreads();

  // logits + distributed softmax; WTf[h][m] = attn*rstd
  int r0 = w * 16 + lk * 4;
  float4 mns = *(const float4*)(MEANR + r0);
  float4 rst = *(const float4*)(RSTDR + r0);
  float mn[4] = { mns.x, mns.y, mns.z, mns.w };
  float rs[4] = { rst.x, rst.y, rst.z, rst.w };
  float Ah = AB[0][l15 & 7], Bh = AB[1][l15 & 7];
  float lg[4];
  #pragma unroll
  for (int j = 0; j < 4; ++j)
    lg[j] = 0.08838834764831845f * (rs[j] * (dacc[j] - mn[j] * Bh) + Ah);
  float lmax = fmaxf(fmaxf(lg[0], lg[1]), fmaxf(lg[2], lg[3]));
  lmax = fmaxf(lmax, __shfl_xor(lmax, 16));
  lmax = fmaxf(lmax, __shfl_xor(lmax, 32));
  if (l < 8) PMAX[w][l] = lmax;
  __syncthreads();
  float gmax = fmaxf(fmaxf(PMAX[0][l15 & 7], PMAX[1][l15 & 7]),
                     fmaxf(PMAX[2][l15 & 7], PMAX[3][l15 & 7]));
  float e4[4]; float ls = 0.f, lm = 0.f;
  #pragma unroll
  for (int j = 0; j < 4; ++j){
    e4[j] = __expf(lg[j] - gmax);
    ls += e4[j];
    lm += e4[j] * rs[j] * mn[j];
  }
  ls += __shfl_xor(ls, 16); ls += __shfl_xor(ls, 32);
  lm += __shfl_xor(lm, 16); lm += __shfl_xor(lm, 32);
  if (l < 8){ PSUM[w][l] = ls; PMU[w][l] = lm; }
  __syncthreads();
  float Sh = PSUM[0][l15 & 7] + PSUM[1][l15 & 7] + PSUM[2][l15 & 7] + PSUM[3][l15 & 7];
  float inv = 1.0f / Sh;
  if (l15 < 8){
    #pragma unroll
    for (int j = 0; j < 4; ++j) WTf[l15][r0 + j] = e4[j] * rs[j] * inv;
  }
  if (w == 0 && l < 8){
    MUH[l] = (PMU[0][l] + PMU[1][l] + PMU[2][l] + PMU[3][l]) * inv;
  }
  __syncthreads();

  // phase2 via MFMA: ctx[h][c] = sum_m WT[h][m]*S[m][c]
  union { ushort_t u[8]; s16x8 v; } af0, af1;
  af0.v = (s16x8){0,0,0,0,0,0,0,0};
  af1.v = (s16x8){0,0,0,0,0,0,0,0};
  if (l15 < 8){
    #pragma unroll
    for (int e = 0; e < 8; ++e){
      af0.u[e] = f2bf(WTf[l15][lk * 8 + e]);
      af1.u[e] = f2bf(WTf[l15][32 + lk * 8 + e]);
    }
  }
  float mu[4];
  #pragma unroll
  for (int j = 0; j < 4; ++j) mu[j] = (lk < 2) ? MUH[lk * 4 + j] : 0.f;

  const char* Sp = (const char*)S;
  #pragma unroll
  for (int ns = 0; ns < 8; ++ns){
    int c = w * 128 + ns * 16 + l15;
    int cch = c >> 3, cb = (c & 7) * 2;
    int sb = cch & 56, cl = cch & 7;
    union { ushort_t u[8]; s16x8 v; } bf0, bf1;
    #pragma unroll
    for (int e = 0; e < 8; ++e){
      int m0 = lk * 8 + e;
      int m1 = m0 + 32;
      bf0.u[e] = *(const ushort_t*)(Sp + m0 * 1024 + ((sb | (cl ^ ((m0 ^ lk) & 7))) << 4) + cb);
      bf1.u[e] = *(const ushort_t*)(Sp + m1 * 1024 + ((sb | (cl ^ ((m1 ^ (4 + lk)) & 7))) << 4) + cb);
    }
    f32x4 cacc = (f32x4){0.f, 0.f, 0.f, 0.f};
    cacc = __builtin_amdgcn_mfma_f32_16x16x32_bf16(af0.v, bf0.v, cacc, 0, 0, 0);
    cacc = __builtin_amdgcn_mfma_f32_16x16x32_bf16(af1.v, bf1.v, cacc, 0, 0, 0);
    if (lk < 2){
      float gc = lgw[c], bc = lbw[c];
      #pragma unroll
      for (int j = 0; j < 4; ++j){
        int h = lk * 4 + j;
        R[(size_t)bb * 4096 + h * 512 + c] = f2bf(gc * (cacc[j] - mu[j]) + bc);
      }
    }
  }
}

// ---------- GEMM core: BM=64 x BN=64 tile, 32KB LDS, 4 blocks/CU (best measured: R9) ----------
#define GLL16(gsrc, ldst) \
  __builtin_amdgcn_global_load_lds((const __attribute__((address_space(1))) unsigned int*)(gsrc), \
                                   (__attribute__((address_space(3))) unsigned int*)(ldst), 16, 0, 0)

struct GDesc {
  const ushort_t* A; const ushort_t* Bt; const float* bias;
  ushort_t* Cb; const ushort_t* R;
  int lda, ldb, ldcb, ldr;
  int gx, startBlock, flags, K;   // flags: 1=GELU 2=BIAS 8=WBF16 16=RESID
};
struct GSet { GDesc d[3]; int nseg; };

__global__ __launch_bounds__(256, 4) void gemmset_k(GSet gs){
  __shared__ ushort_t smA[2][64 * 64];
  __shared__ ushort_t smB[2][64 * 64];
  int bid = blockIdx.x, tid = threadIdx.x, lane = tid & 63, w = tid >> 6;
  int seg = 0;
  #pragma unroll
  for (int i = 1; i < 3; ++i) if (i < gs.nseg && bid >= gs.d[i].startBlock) seg = i;
  GDesc g = gs.d[seg];
  int lid = bid - g.startBlock;
  {
    int nwg = (seg + 1 < gs.nseg ? gs.d[seg + 1].startBlock : (int)gridDim.x) - g.startBlock;
    int q = nwg >> 3;
    lid = (lid & 7) * q + (lid >> 3);
  }
  int bx = lid % g.gx, by = lid / g.gx;
  int m0 = by * 64, n0 = bx * 64;
  int nk = g.K >> 6;

  auto stage = [&](int buf, int kt){
    int k0 = kt << 6;
    #pragma unroll
    for (int i = 0; i < 2; ++i){
      int c = ((w << 1) + i) * 64 + lane;
      int rowl = c >> 3, sp = c & 7;
      int sg = sp ^ (rowl & 7);
      GLL16(g.A + (size_t)(m0 + rowl) * g.lda + (k0 + sg * 8), &smA[buf][((w << 1) + i) * 512]);
    }
    #pragma unroll
    for (int i = 0; i < 2; ++i){
      int c = ((w << 1) + i) * 64 + lane;
      int rowl = c >> 3, sp = c & 7;
      int sg = sp ^ (rowl & 7);
      GLL16(g.Bt + (size_t)(n0 + rowl) * g.ldb + (k0 + sg * 8), &smB[buf][((w << 1) + i) * 512]);
    }
  };

  int qrow = w >> 1, qcol = w & 1;
  int l15 = lane & 15, lk = lane >> 4, l7 = lane & 7;
  int sb0 = ((0 + lk) ^ l7) << 4;
  int sb1 = ((4 + lk) ^ l7) << 4;
  int arow = (qrow * 32 + l15) * 128;
  int brow = (qcol * 32 + l15) * 128;

  f32x4 acc[2][2];
  #pragma unroll
  for (int m = 0; m < 2; ++m)
    #pragma unroll
    for (int n = 0; n < 2; ++n)
      acc[m][n] = (f32x4){0.f, 0.f, 0.f, 0.f};

  stage(0, 0);
  asm volatile("s_waitcnt vmcnt(0)" ::: "memory");
  __syncthreads();
  for (int kt = 0; kt < nk; ++kt){
    int cur = kt & 1;
    if (kt + 1 < nk) stage((kt + 1) & 1, kt + 1);
    const char* ab = (const char*)&smA[cur][0];
    const char* bbp = (const char*)&smB[cur][0];
    s16x8 af[2][2], bfv[2][2];
    #pragma unroll
    for (int m = 0; m < 2; ++m){
      af[m][0] = *(const s16x8*)(ab + arow + m * 2048 + sb0);
      af[m][1] = *(const s16x8*)(ab + arow + m * 2048 + sb1);
    }
    #pragma unroll
    for (int n = 0; n < 2; ++n){
      bfv[n][0] = *(const s16x8*)(bbp + brow + n * 2048 + sb0);
      bfv[n][1] = *(const s16x8*)(bbp + brow + n * 2048 + sb1);
    }
    #pragma unroll
    for (int kb = 0; kb < 2; ++kb)
      #pragma unroll
      for (int m = 0; m < 2; ++m)
        #pragma unroll
        for (int n = 0; n < 2; ++n)
          acc[m][n] = __builtin_amdgcn_mfma_f32_16x16x32_bf16(af[m][kb], bfv[n][kb], acc[m][n], 0, 0, 0);
    asm volatile("s_waitcnt vmcnt(0)" ::: "memory");
    __syncthreads();
  }

  bool fGELU = g.flags & 1, fBIAS = g.flags & 2, fRES = g.flags & 16;
  #pragma unroll
  for (int n = 0; n < 2; ++n){
    int col = n0 + qcol * 32 + n * 16 + l15;
    float bvv = fBIAS ? g.bias[col] : 0.0f;
    #pragma unroll
    for (int m = 0; m < 2; ++m){
      int rbase = m0 + qrow * 32 + m * 16 + lk * 4;
      #pragma unroll
      for (int r = 0; r < 4; ++r){
        float x = acc[m][n][r] + bvv;
        if (fGELU) x = gelu_f(x);
        int row = rbase + r;
        if (fRES) x += bf2f(g.R[(size_t)row * g.ldr + col]);
        g.Cb[(size_t)row * g.ldcb + col] = f2bf(x);
      }
    }
  }
}

template<bool GELU, bool BIAS, bool WF32, bool WBF16, bool RESID>
__global__ __launch_bounds__(256, 4) void gemm_k(
    const ushort_t* __restrict__ A, int lda, long long aZ,
    const ushort_t* __restrict__ Bt, int ldb, long long bZ,
    const float* __restrict__ bias, long long biasZ,
    float* __restrict__ C, int ldc, long long cZ,
    ushort_t* __restrict__ Cb, int ldcb, long long cbZ,
    const ushort_t* __restrict__ R, int ldr,
    int M, int N, int K)
{
  __shared__ ushort_t smA[2][64 * 64];
  __shared__ ushort_t smB[2][64 * 64];
  int tid = threadIdx.x, lane = tid & 63, w = tid >> 6;
  int z = blockIdx.z;
  A  += (size_t)aZ * z;
  Bt += (size_t)bZ * z;
  if (BIAS)  bias += (size_t)biasZ * z;
  if (WF32)  C    += (size_t)cZ * z;
  if (WBF16) Cb   += (size_t)cbZ * z;

  int gx = gridDim.x, gy = gridDim.y;
  int nwg = gx * gy;
  int bx = blockIdx.x, by = blockIdx.y;
  if ((nwg & 7) == 0 && (gx & (gx - 1)) == 0){
    int lid = bx + gx * by;
    int cpx = nwg >> 3;
    int slid = (lid & 7) * cpx + (lid >> 3);
    int lgx = 31 - __clz(gx);
    bx = slid & (gx - 1);
    by = slid >> lgx;
  }
  int m0 = by * 64, n0 = bx * 64;
  int nk = K >> 6;

  auto stage = [&](int buf, int kt){
    int k0 = kt << 6;
    #pragma unroll
    for (int i = 0; i < 2; ++i){
      int c = ((w << 1) + i) * 64 + lane;
      int rowl = c >> 3, sp = c & 7;
      int sg = sp ^ (rowl & 7);
      GLL16(A + (size_t)(m0 + rowl) * lda + (k0 + sg * 8), &smA[buf][((w << 1) + i) * 512]);
    }
    #pragma unroll
    for (int i = 0; i < 2; ++i){
      int c = ((w << 1) + i) * 64 + lane;
      int rowl = c >> 3, sp = c & 7;
      int sg = sp ^ (rowl & 7);
      GLL16(Bt + (size_t)(n0 + rowl) * ldb + (k0 + sg * 8), &smB[buf][((w << 1) + i) * 512]);
    }
  };

  int qrow = w >> 1, qcol = w & 1;
  int l15 = lane & 15, lk = lane >> 4, l7 = lane & 7;
  int sb0 = ((0 + lk) ^ l7) << 4;
  int sb1 = ((4 + lk) ^ l7) << 4;
  int arow = (qrow * 32 + l15) * 128;
  int brow = (qcol * 32 + l15) * 128;

  f32x4 acc[2][2];
  #pragma unroll
  for (int m = 0; m < 2; ++m)
    #pragma unroll
    for (int n = 0; n < 2; ++n)
      acc[m][n] = (f32x4){0.f, 0.f, 0.f, 0.f};

  stage(0, 0);
  asm volatile("s_waitcnt vmcnt(0)" ::: "memory");
  __syncthreads();
  for (int kt = 0; kt < nk; ++kt){
    int cur = kt & 1;
    if (kt + 1 < nk) stage((kt + 1) & 1, kt + 1);
    const char* ab = (const char*)&smA[cur][0];
    const char* bbp = (const char*)&smB[cur][0];
    s16x8 af[2][2], bfv[2][2];
    #pragma unroll
    for (int m = 0; m < 2; ++m){
      af[m][0] = *(const s16x8*)(ab + arow + m * 2048 + sb0);
      af[m][1] = *(const s16x8*)(ab + arow + m * 2048 + sb1);
    }
    #pragma unroll
    for (int n = 0; n < 2; ++n){
      bfv[n][0] = *(const s16x8*)(bbp + brow + n * 2048 + sb0);
      bfv[n][1] = *(const s16x8*)(bbp + brow + n * 2048 + sb1);
    }
    #pragma unroll
    for (int kb = 0; kb < 2; ++kb)
      #pragma unroll
      for (int m = 0; m < 2; ++m)
        #pragma unroll
        for (int n = 0; n < 2; ++n)
          acc[m][n] = __builtin_amdgcn_mfma_f32_16x16x32_bf16(af[m][kb], bfv[n][kb], acc[m][n], 0, 0, 0);
    asm volatile("s_waitcnt vmcnt(0)" ::: "memory");
    __syncthreads();
  }

  #pragma unroll
  for (int n = 0; n < 2; ++n){
    int col = n0 + qcol * 32 + n * 16 + l15;
    float bvv = BIAS ? bias[col] : 0.0f;
    #pragma unroll
    for (int m = 0; m < 2; ++m){
      int rbase = m0 + qrow * 32 + m * 16 + lk * 4;
      #pragma unroll
      for (int r = 0; r < 4; ++r){
        float x = acc[m][n][r] + bvv;
        if (GELU) x = gelu_f(x);
        int row = rbase + r;
        if (RESID) x += bf2f(R[(size_t)row * ldr + col]);
        if (WF32)  C[(size_t)row * ldc + col] = x;
        if (WBF16) Cb[(size_t)row * ldcb + col] = f2bf(x);
      }
    }
  }
}

// ---------- host ----------
extern "C" void kernel_launch(void* const* d_in, const int* in_sizes, int n_in,
                              void* d_out, int out_size, void* d_ws, size_t ws_size,
                              hipStream_t stream)
{
  (void)in_sizes; (void)n_in; (void)out_size;
  const float* states      = (const float*)d_in[0];
  const float* time_values = (const float*)d_in[1];
  const float* class_sum   = (const float*)d_in[2];
  const float* support     = (const float*)d_in[3];
  const float* trunk_ln_g  = (const float*)d_in[4];
  const float* trunk_ln_b  = (const float*)d_in[5];
  const float* trunk_w1    = (const float*)d_in[6];
  const float* trunk_b1    = (const float*)d_in[7];
  const float* trunk_w2    = (const float*)d_in[8];
  const float* trunk_b2    = (const float*)d_in[9];
  const float* mem_ln_g    = (const float*)d_in[10];
  const float* mem_ln_b    = (const float*)d_in[11];
  const float* mem_w       = (const float*)d_in[12];
  const float* mem_b       = (const float*)d_in[13];
  const float* wq          = (const float*)d_in[14];
  const float* bq          = (const float*)d_in[15];
  const float* wk          = (const float*)d_in[16];
  /* d_in[17] = bk: unused (softmax shift invariance) */
  const float* wv          = (const float*)d_in[18];
  const float* bvp         = (const float*)d_in[19];
  const float* wo          = (const float*)d_in[20];
  const float* bo          = (const float*)d_in[21];
  const float* pre_g       = (const float*)d_in[22];
  const float* pre_b       = (const float*)d_in[23];
  const float* film_w      = (const float*)d_in[24];
  const float* film_b      = (const float*)d_in[25];
  const float* cond_g      = (const float*)d_in[26];
  const float* cond_b      = (const float*)d_in[27];
  const float* cond_w1     = (const float*)d_in[28];
  const float* cond_b1     = (const float*)d_in[29];
  const float* cond_w2     = (const float*)d_in[30];
  const float* cond_b2     = (const float*)d_in[31];
  const float* head_g      = (const float*)d_in[32];
  const float* head_bb     = (const float*)d_in[33];
  const float* head_w1     = (const float*)d_in[34];
  const float* head_b1     = (const float*)d_in[35];
  const float* head_w2     = (const float*)d_in[36];
  const float* head_b2     = (const float*)d_in[37];
  float* out = (float*)d_out;

  char* ws = (char*)d_ws;
  size_t off = 0;
  auto alloc = [&](size_t bytes)->char*{
    char* p = ws + off;
    off += (bytes + 255) & ~(size_t)255;
    return p;
  };
  ushort_t* tw1T   = (ushort_t*)alloc((size_t)640 * 1024 * 2);
  ushort_t* tw2T   = (ushort_t*)alloc((size_t)1024 * 1024 * 2);
  ushort_t* wqT    = (ushort_t*)alloc((size_t)1024 * 1024 * 2);
  ushort_t* wkT    = (ushort_t*)alloc((size_t)1024 * 1024 * 2);
  ushort_t* wvT    = (ushort_t*)alloc((size_t)1024 * 1024 * 2);
  ushort_t* woT    = (ushort_t*)alloc((size_t)1024 * 1024 * 2);
  ushort_t* memw_b = (ushort_t*)alloc((size_t)512 * 1024 * 2);
  ushort_t* filmWT = (ushort_t*)alloc((size_t)512 * 2048 * 2);
  ushort_t* cw1T   = (ushort_t*)alloc((size_t)1024 * 1024 * 2);
  ushort_t* cw2T   = (ushort_t*)alloc((size_t)1024 * 1024 * 2);
  ushort_t* hw1T   = (ushort_t*)alloc((size_t)1024 * 1024 * 2);
  ushort_t* hw2T   = (ushort_t*)alloc((size_t)1024 * 512 * 2);
  ushort_t* K2     = (ushort_t*)alloc((size_t)512 * 1024 * 2);
  ushort_t* V2T    = (ushort_t*)alloc((size_t)1024 * 512 * 2);
  float*    bv2    = (float*)   alloc((size_t)1024 * 4);
  ushort_t* xnb    = (ushort_t*)alloc((size_t)4096 * 640 * 2);
  ushort_t* h1     = (ushort_t*)alloc((size_t)4096 * 1024 * 2);
  ushort_t* gb     = (ushort_t*)alloc((size_t)4096 * 1024 * 2);
  ushort_t* qb     = (ushort_t*)alloc((size_t)4096 * 1024 * 2);
  ushort_t* U      = (ushort_t*)alloc((size_t)4096 * 4096 * 2);
  ushort_t* Rb     = (ushort_t*)alloc((size_t)4096 * 4096 * 2);
  ushort_t* sumb   = (ushort_t*)alloc((size_t)4096 * 1024 * 2);
  ushort_t* combb  = (ushort_t*)alloc((size_t)4096 * 1024 * 2);
  ushort_t* csb    = (ushort_t*)alloc((size_t)4096 * 512 * 2);
  ushort_t* filmb  = (ushort_t*)alloc((size_t)4096 * 2048 * 2);
  ushort_t* c2b    = (ushort_t*)alloc((size_t)4096 * 1024 * 2);
  ushort_t* cxb    = (ushort_t*)alloc((size_t)4096 * 1024 * 2);
  ushort_t* c1     = (ushort_t*)alloc((size_t)4096 * 1024 * 2);
  ushort_t* cond2b = (ushort_t*)alloc((size_t)4096 * 1024 * 2);
  ushort_t* hxb    = (ushort_t*)alloc((size_t)4096 * 1024 * 2);
  ushort_t* h3     = (ushort_t*)alloc((size_t)4096 * 1024 * 2);
  if (off > ws_size) return;

  PrepArgs pa;
  pa.states = states; pa.tv = time_values; pa.lng = trunk_ln_g; pa.lnb = trunk_ln_b; pa.xnb = xnb;
  int s = 0;
  auto setT = [&](int i, const float* in, ushort_t* o, int K, int N){
    pa.t[i].in = in; pa.t[i].out = o; pa.t[i].K = K; pa.t[i].N = N; pa.t[i].start = s;
    s += (N >> 5) * (K >> 5);
  };
  setT(0, trunk_w1, tw1T, 640, 1024);
  setT(1, trunk_w2, tw2T, 1024, 1024);
  setT(2, wq, wqT, 1024, 1024);
  setT(3, wk, wkT, 1024, 1024);
  setT(4, wv, wvT, 1024, 1024);
  setT(5, wo, woT, 1024, 1024);
  setT(6, film_w, filmWT, 512, 2048);
  setT(7, cond_w1, cw1T, 1024, 1024);
  setT(8, cond_w2, cw2T, 1024, 1024);
  setT(9, head_w1, hw1T, 1024, 1024);
  setT(10, head_w2, hw2T, 1024, 512);
  pa.ntiles_end = s;
  pa.cast1_blocks = (512 * 1024) / 1024;
  pa.cast_end = s + pa.cast1_blocks + (4096 * 512) / 1024;
  pa.memw = mem_w; pa.memwb = memw_b;
  pa.csum = class_sum; pa.csb = csb;
  pa.memb = mem_b; pa.wv = wv; pa.bvp = bvp; pa.bv2 = bv2;
  prep_k<<<4096 + pa.cast_end + 4, 256, 0, stream>>>(pa);

  // merged set A: K2, V2T, h1  (all dep only on prep)
  {
    GSet gs; gs.nseg = 3;
    gs.d[0] = { memw_b, wkT, nullptr, K2, nullptr, 1024, 1024, 1024, 0, 16, 0, 8, 1024 };
    gs.d[1] = { wvT, memw_b, nullptr, V2T, nullptr, 1024, 1024, 512, 0, 8, 128, 8, 1024 };
    gs.d[2] = { xnb, tw1T, trunk_b1, h1, nullptr, 640, 640, 1024, 0, 16, 256, 1|2|8, 640 };
    gemmset_k<<<1280, 256, 0, stream>>>(gs);
  }

  gemm_k<false, true, false, true, false><<<dim3(16, 64, 1), 256, 0, stream>>>(
      h1, 1024, 0, tw2T, 1024, 0, trunk_b2, 0, nullptr, 0, 0, gb, 1024, 0, nullptr, 0, 4096, 1024, 1024);

  // merged set B: qb (dep gb), film (dep prep)
  {
    GSet gs; gs.nseg = 2;
    gs.d[0] = { gb, wqT, bq, qb, nullptr, 1024, 1024, 1024, 0, 16, 0, 2|8, 1024 };
    gs.d[1] = { csb, filmWT, film_b, filmb, nullptr, 512, 512, 2048, 0, 32, 1024, 2|8, 512 };
    gs.d[2] = gs.d[1];
    gemmset_k<<<3072, 256, 0, stream>>>(gs);
  }

  gemm_k<false, false, false, true, false><<<dim3(8, 64, 8), 256, 0, stream>>>(
      qb, 1024, 128, K2, 1024, 128, nullptr, 0, nullptr, 0, 0, U, 4096, 512, nullptr, 0, 4096, 512, 128);

  suppattn_k<<<4096, 256, 0, stream>>>(support, mem_ln_g, mem_ln_b, U, Rb);

  gemm_k<false, true, false, true, false><<<dim3(2, 64, 8), 256, 0, stream>>>(
      Rb, 4096, 512, V2T, 512, 65536, bv2, 128, nullptr, 0, 0, sumb, 1024, 128, nullptr, 0, 4096, 128, 512);

  // combined = sumb@wo + bo + g  (bf16 residual fused in epilogue)
  gemm_k<false, true, false, true, true><<<dim3(16, 64, 1), 256, 0, stream>>>(
      sumb, 1024, 0, woT, 1024, 0, bo, 0, nullptr, 0, 0, combb, 1024, 0, gb, 1024, 4096, 1024, 1024);

  fuse_film_k<<<4096, 256, 0, stream>>>(combb, filmb, pre_g, pre_b, cond_g, cond_b, c2b, cxb);

  gemm_k<true, true, false, true, false><<<dim3(16, 64, 1), 256, 0, stream>>>(
      cxb, 1024, 0, cw1T, 1024, 0, cond_b1, 0, nullptr, 0, 0, c1, 1024, 0, nullptr, 0, 4096, 1024, 1024);
  gemm_k<false, true, false, true, true><<<dim3(16, 64, 1), 256, 0, stream>>>(
      c1, 1024, 0, cw2T, 1024, 0, cond_b2, 0, nullptr, 0, 0, cond2b, 1024, 0, c2b, 1024, 4096, 1024, 1024);
  ln_rows_k<<<4096, 256, 0, stream>>>(cond2b, head_g, head_bb, hxb, 1024);
  gemm_k<true, true, false, true, false><<<dim3(16, 64, 1), 256, 0, stream>>>(
      hxb, 1024, 0, hw1T, 1024, 0, head_b1, 0, nullptr, 0, 0, h3, 1024, 0, nullptr, 0, 4096, 1024, 1024);
  gemm_k<false, true, true, false, false><<<dim3(8, 64, 1), 256, 0, stream>>>(
      h3, 1024, 0, hw2T, 1024, 0, head_b2, 0, out, 512, 0, nullptr, 0, 0, nullptr, 0, 4096, 512, 1024);
}